// Round 9
// baseline (750.494 us; speedup 1.0000x reference)
//
#include <hip/hip_runtime.h>

// MultiHeadAttentionConvIndex — round 15: edge-order vals rows + eidx CSR.
// R14: scalar weights restored (SGPR112, 0 conflicts) but 210us — cost is
// the 208B-row scatter-store at random CSR slots: rows straddle lines ->
// L2 write-allocate RMW (~80MB of FETCH) + 64-way scattered store addrs.
// Now: vals rows stored at row=e (wave writes a dense 13KB span, full-line
// writes, no RMW); CSR order lives in eidx[slot]=e (4B scatter via the
// even wave's atomicAdd). gather reads rows via eidx indirection (reads
// stay 52-lane contiguous per row). Accumulation order class unchanged.
//
// ws: vals[E*52 u32] | U/agg alias [N*96 f32] | cntF[N] | cnti[N] offs[N]
//     curs[N] | bsum[NB] | eidx[E]

#define NEG 0.01f

__device__ __forceinline__ float lrelu(float v) { return v > 0.f ? v : NEG * v; }

__device__ __forceinline__ unsigned bfpack2(float a, float b) {
    unsigned ua = __float_as_uint(a); ua = (ua + 0x7fff + ((ua >> 16) & 1)) >> 16;
    unsigned ub = __float_as_uint(b); ub = (ub + 0x7fff + ((ub >> 16) & 1)) >> 16;
    return ua | (ub << 16);
}

__global__ void zero_kernel(float* __restrict__ p, long n) {
    long i = ((long)blockIdx.x * 256 + threadIdx.x) * 4;
    if (i + 3 < n) {
        *(float4*)(p + i) = make_float4(0.f, 0.f, 0.f, 0.f);
    } else {
        for (long k = i; k < n; ++k) p[k] = 0.f;
    }
}

__global__ void hist_kernel(const int* __restrict__ ei, int* __restrict__ cnt, int E) {
    int e = blockIdx.x * 256 + threadIdx.x;
    if (e < E) atomicAdd(&cnt[ei[E + e]], 1);
}

// ---- fallback serial scan (used only if NB > 1024) ----
__global__ __launch_bounds__(1024)
void scan_kernel(const int* __restrict__ cnt, int* __restrict__ offs,
                 int* __restrict__ curs, int N) {
    __shared__ int ls[1024];
    int tid = threadIdx.x;
    int chunk = (N + 1023) >> 10;
    int lo = tid * chunk;
    int hi = lo + chunk; if (hi > N) hi = N; if (lo > N) lo = N;
    int s = 0;
    for (int i = lo; i < hi; ++i) s += cnt[i];
    ls[tid] = s;
    __syncthreads();
    for (int off = 1; off < 1024; off <<= 1) {
        int v = 0;
        if (tid >= off) v = ls[tid - off];
        __syncthreads();
        ls[tid] += v;
        __syncthreads();
    }
    int run = ls[tid] - s;
    for (int i = lo; i < hi; ++i) {
        offs[i] = run; curs[i] = run; run += cnt[i];
    }
}

// ---- parallel scan, phase 1: per-1024-chunk sums ----
__global__ __launch_bounds__(256)
void blocksum_kernel(const int* __restrict__ cnt, int* __restrict__ bsum, int N) {
    int base = blockIdx.x * 1024;
    int tid = threadIdx.x;
    int v = 0;
#pragma unroll
    for (int r = 0; r < 4; ++r) {
        int idx = base + r * 256 + tid;
        if (idx < N) v += cnt[idx];
    }
#pragma unroll
    for (int d = 32; d > 0; d >>= 1) v += __shfl_down(v, d, 64);
    __shared__ int ws[4];
    int wv = tid >> 6, lane = tid & 63;
    if (lane == 0) ws[wv] = v;
    __syncthreads();
    if (tid == 0) bsum[blockIdx.x] = ws[0] + ws[1] + ws[2] + ws[3];
}

// ---- phase 2: exclusive scan of NB (<=1024) block sums, in place ----
__global__ __launch_bounds__(1024)
void bscan_kernel(int* __restrict__ bsum, int NB) {
    __shared__ int ls[1024];
    int tid = threadIdx.x;
    int v = (tid < NB) ? bsum[tid] : 0;
    ls[tid] = v;
    __syncthreads();
    for (int off = 1; off < 1024; off <<= 1) {
        int t = 0;
        if (tid >= off) t = ls[tid - off];
        __syncthreads();
        ls[tid] += t;
        __syncthreads();
    }
    if (tid < NB) bsum[tid] = ls[tid] - v;   // exclusive
}

// ---- phase 3: block-local scan + block offset -> offs/curs ----
__global__ __launch_bounds__(1024)
void offs_kernel(const int* __restrict__ cnt, const int* __restrict__ boff,
                 int* __restrict__ offs, int* __restrict__ curs, int N) {
    int tid = threadIdx.x;
    int i = blockIdx.x * 1024 + tid;
    int lane = tid & 63, wv = tid >> 6;
    int c = (i < N) ? cnt[i] : 0;
    int v = c;
#pragma unroll
    for (int d = 1; d < 64; d <<= 1) {
        int t = __shfl_up(v, d, 64);
        if (lane >= d) v += t;
    }
    __shared__ int ws[16];
    if (lane == 63) ws[wv] = v;
    __syncthreads();
    if (wv == 0) {
        int wvv = (lane < 16) ? ws[lane] : 0;
#pragma unroll
        for (int d = 1; d < 16; d <<= 1) {
            int t = __shfl_up(wvv, d, 64);
            if (lane >= d) wvv += t;
        }
        if (lane < 16) ws[lane] = wvv;       // inclusive wave sums
    }
    __syncthreads();
    int waveoff = (wv > 0) ? ws[wv - 1] : 0;
    int excl = v - c + waveoff + boff[blockIdx.x];
    if (i < N) { offs[i] = excl; curs[i] = excl; }
}

// U = x @ Wp[0:64,:] + bp   ([N,64]@[64,96], dense)
// 64 nodes/block; thread = (node, 24-col group).
__global__ __launch_bounds__(256, 4)
void pre_kernel(const float* __restrict__ x, const float* __restrict__ Wp,
                const float* __restrict__ bp, float* __restrict__ U, int N)
{
    __shared__ float xs[64][65];
    int n0 = blockIdx.x * 64;
    for (int p = threadIdx.x; p < 64 * 16; p += 256) {
        int row = p >> 4, f4 = p & 15;
        int n = n0 + row;
        float4 v = make_float4(0.f, 0.f, 0.f, 0.f);
        if (n < N) v = ((const float4*)(x + (long)n * 64))[f4];
        xs[row][f4 * 4 + 0] = v.x; xs[row][f4 * 4 + 1] = v.y;
        xs[row][f4 * 4 + 2] = v.z; xs[row][f4 * 4 + 3] = v.w;
    }
    __syncthreads();

    int node = threadIdx.x >> 2;
    int cg = threadIdx.x & 3;           // 4 col-groups of 24
    float4 acc[6];
#pragma unroll
    for (int c = 0; c < 6; ++c) acc[c] = ((const float4*)(bp + cg * 24))[c];
    for (int k = 0; k < 64; ++k) {
        float xv = xs[node][k];
        const float* wr = Wp + k * 96 + cg * 24;
#pragma unroll
        for (int c = 0; c < 6; ++c) {
            float4 w = ((const float4*)wr)[c];
            acc[c].x += xv * w.x; acc[c].y += xv * w.y;
            acc[c].z += xv * w.z; acc[c].w += xv * w.w;
        }
    }
    int n = n0 + node;
    if (n < N) {
#pragma unroll
        for (int c = 0; c < 6; ++c)
            ((float4*)(U + (long)n * 96 + cg * 24))[c] = acc[c];
    }
}

// Wave-half per edge: block = 4 waves = 2 pairs; pair covers 64 edges.
// wave half=0: cols 0-47 + CSR eidx fill; half=1: cols 48-95 + p store.
// vals rows stored at row=e (dense coalesced writes, no RMW).
__global__ __launch_bounds__(256, 1)
void edge_msg_kernel(const float* __restrict__ U, const float* __restrict__ ea,
                     const int* __restrict__ ei,
                     const float* __restrict__ Wp,
                     const float* __restrict__ Wa, const float* __restrict__ ba,
                     unsigned* __restrict__ vals, int* __restrict__ curs,
                     int* __restrict__ eidx, int E)
{
    __shared__ float ex[4][2][64];   // logit partials per pair per lane, 2 KB

    int lane = threadIdx.x & 63;
    int wid  = threadIdx.x >> 6;                                  // 0..3
    int half = __builtin_amdgcn_readfirstlane(wid & 1);           // SGPR
    int pl   = __builtin_amdgcn_readfirstlane(wid >> 1);          // pair 0/1
    int e = (blockIdx.x * 2 + pl) * 64 + lane;
    bool active = (e < E);
    int ec = active ? e : (E - 1);
    int src = ei[ec];
    int dst = ei[E + ec];

    // CSR permutation fill (even wave): 4B scatter, latency hides under GEMM
    if (half == 0 && active) {
        int pos = atomicAdd(&curs[dst], 1);
        eidx[pos] = e;
    }

    float4 S[12];
    const float4* Urow = (const float4*)(U + (long)src * 96 + half * 48);
#pragma unroll
    for (int j = 0; j < 12; ++j) S[j] = Urow[j];

    const float* erow = ea + (long)ec * 32;
    const float* Wh = Wp + 64 * 96 + half * 48;   // scalar base

#pragma unroll 1
    for (int kc = 0; kc < 8; ++kc) {              // 8 chunks of 4 edge feats
        float4 c = ((const float4*)erow)[kc];
        const float* W0 = Wh + (4 * kc + 0) * 96;
        const float* W1 = Wh + (4 * kc + 1) * 96;
        const float* W2 = Wh + (4 * kc + 2) * 96;
        const float* W3 = Wh + (4 * kc + 3) * 96;
#pragma unroll
        for (int j = 0; j < 12; ++j) {
            float4 w0 = ((const float4*)W0)[j];   // wave-uniform -> s_load
            float4 w1 = ((const float4*)W1)[j];
            float4 w2 = ((const float4*)W2)[j];
            float4 w3 = ((const float4*)W3)[j];
            S[j].x += c.x * w0.x + c.y * w1.x + c.z * w2.x + c.w * w3.x;
            S[j].y += c.x * w0.y + c.y * w1.y + c.z * w2.y + c.w * w3.y;
            S[j].z += c.x * w0.z + c.y * w1.z + c.z * w2.z + c.w * w3.z;
            S[j].w += c.x * w0.w + c.y * w1.w + c.z * w2.w + c.w * w3.w;
        }
    }
#pragma unroll
    for (int j = 0; j < 12; ++j) {
        S[j].x = lrelu(S[j].x); S[j].y = lrelu(S[j].y);
        S[j].z = lrelu(S[j].z); S[j].w = lrelu(S[j].w);
    }

    // partial logits over this half's 48 cols (Wa rows wave-uniform -> s_load)
    float l0 = 0.f, l1 = 0.f, l2 = 0.f, l3 = 0.f;
    const float* Wah = Wa + half * 48 * 4;
#pragma unroll
    for (int j = 0; j < 12; ++j) {
        float4 m = S[j];
        float4 w0 = ((const float4*)(Wah + (4 * j + 0) * 4))[0];
        float4 w1 = ((const float4*)(Wah + (4 * j + 1) * 4))[0];
        float4 w2 = ((const float4*)(Wah + (4 * j + 2) * 4))[0];
        float4 w3 = ((const float4*)(Wah + (4 * j + 3) * 4))[0];
        l0 += m.x * w0.x + m.y * w1.x + m.z * w2.x + m.w * w3.x;
        l1 += m.x * w0.y + m.y * w1.y + m.z * w2.y + m.w * w3.y;
        l2 += m.x * w0.z + m.y * w1.z + m.z * w2.z + m.w * w3.z;
        l3 += m.x * w0.w + m.y * w1.w + m.z * w2.w + m.w * w3.w;
    }

    // pair exchange: even wave publishes partial logits
    if (half == 0) {
        ex[0][pl][lane] = l0; ex[1][pl][lane] = l1;
        ex[2][pl][lane] = l2; ex[3][pl][lane] = l3;
    }
    __syncthreads();
    if (half == 1) {
        l0 += ex[0][pl][lane]; l1 += ex[1][pl][lane];
        l2 += ex[2][pl][lane]; l3 += ex[3][pl][lane];
    }

    if (active) {
        unsigned* rowb = vals + (long)e * 52;     // edge-order: dense span
        unsigned* row = rowb + half * 24;
#pragma unroll
        for (int j2 = 0; j2 < 6; ++j2) {          // 6 x dwordx4 per half
            uint4 u;
            u.x = bfpack2(S[2 * j2].x,     S[2 * j2].y);
            u.y = bfpack2(S[2 * j2].z,     S[2 * j2].w);
            u.z = bfpack2(S[2 * j2 + 1].x, S[2 * j2 + 1].y);
            u.w = bfpack2(S[2 * j2 + 1].z, S[2 * j2 + 1].w);
            ((uint4*)row)[j2] = u;
        }
        if (half == 1) {
            float p0 = __expf(l0 + ba[0]), p1 = __expf(l1 + ba[1]);
            float p2 = __expf(l2 + ba[2]), p3 = __expf(l3 + ba[3]);
            ((uint4*)rowb)[12] = make_uint4(__float_as_uint(p0), __float_as_uint(p1),
                                            __float_as_uint(p2), __float_as_uint(p3));
        }
    }
}

// One wave per node: T_h = sum_e p_h*msg_e; then agg = (T_h/sum p_h)@Wv + bv.
// Rows located via eidx[slot] indirection (vals stored in edge order).
// Shfl sources 48..51 are active inside the lane<52 scope (R3 lesson).
__global__ __launch_bounds__(512)
void gather_kernel(const unsigned* __restrict__ vals, const int* __restrict__ offs,
                   const int* __restrict__ cnt, const int* __restrict__ eidx,
                   const float* __restrict__ Wv, const float* __restrict__ bv,
                   float* __restrict__ agg, float* __restrict__ cntF, int N)
{
    __shared__ __attribute__((aligned(16))) float Wvs[96][96];  // 36 KB
    __shared__ float Tls[8][4][96];                             // 12 KB
    int wv = threadIdx.x >> 6;
    int lane = threadIdx.x & 63;
    int node = blockIdx.x * 8 + wv;
    bool nvalid = (node < N);

    // cooperative Wv stage: 2304 float4s over 512 threads
    for (int i = threadIdx.x; i < 96 * 24; i += 512)
        ((float4*)Wvs)[i] = ((const float4*)Wv)[i];
    __syncthreads();   // no early returns above: all 8 waves arrive

    int start = nvalid ? offs[node] : 0;
    int deg   = nvalid ? cnt[node] : 0;

    float s0[4] = {0.f, 0.f, 0.f, 0.f};
    float s1[4] = {0.f, 0.f, 0.f, 0.f};
    float d0 = 0.f, d1 = 0.f, d2 = 0.f, d3 = 0.f;
    if (lane < 52) {
        // Lanes 48..51 accumulate garbage (their own p-bits as "msg"), but
        // never store it — keeping them in removes per-row exec-mask flips.
#define PROC(v) {                                                   \
        float vf = __uint_as_float(v);                              \
        float q0 = __shfl(vf, 48, 64);                              \
        float q1 = __shfl(vf, 49, 64);                              \
        float q2 = __shfl(vf, 50, 64);                              \
        float q3 = __shfl(vf, 51, 64);                              \
        float m0 = __uint_as_float((v) << 16);                      \
        float m1 = __uint_as_float((v) & 0xffff0000u);              \
        s0[0] += q0 * m0; s1[0] += q0 * m1;                         \
        s0[1] += q1 * m0; s1[1] += q1 * m1;                         \
        s0[2] += q2 * m0; s1[2] += q2 * m1;                         \
        s0[3] += q3 * m0; s1[3] += q3 * m1;                         \
        d0 += q0; d1 += q1; d2 += q2; d3 += q3; }
        const int* eix = eidx + start;
        int r = 0;
        for (; r + 4 <= deg; r += 4) {           // 4 row loads in flight
            long o0 = (long)eix[r]     * 52;
            long o1 = (long)eix[r + 1] * 52;
            long o2 = (long)eix[r + 2] * 52;
            long o3 = (long)eix[r + 3] * 52;
            unsigned va = vals[o0 + lane];
            unsigned vb = vals[o1 + lane];
            unsigned vc = vals[o2 + lane];
            unsigned vd = vals[o3 + lane];
            PROC(va) PROC(vb) PROC(vc) PROC(vd)
        }
        for (; r < deg; ++r) {
            unsigned v = vals[(long)eix[r] * 52 + lane];
            PROC(v)
        }
#undef PROC
    }
    if (lane < 48) {
        float r0 = (deg > 0) ? 1.f / d0 : 0.f;
        float r1 = (deg > 0) ? 1.f / d1 : 0.f;
        float r2 = (deg > 0) ? 1.f / d2 : 0.f;
        float r3 = (deg > 0) ? 1.f / d3 : 0.f;
        Tls[wv][0][2 * lane] = s0[0] * r0; Tls[wv][0][2 * lane + 1] = s1[0] * r0;
        Tls[wv][1][2 * lane] = s0[1] * r1; Tls[wv][1][2 * lane + 1] = s1[1] * r1;
        Tls[wv][2][2 * lane] = s0[2] * r2; Tls[wv][2][2 * lane + 1] = s1[2] * r2;
        Tls[wv][3][2 * lane] = s0[3] * r3; Tls[wv][3][2 * lane + 1] = s1[3] * r3;
    }
    // Same-wave LDS producer/consumer for Tls[wv]: lgkmcnt wait is
    // compiler-inserted; no block barrier needed. Wvs was barriered above.
    if (nvalid) {
        if (lane < 48) {
            int j = 2 * lane;                      // output cols j, j+1
            int h = lane / 12;                     // head (pairs never straddle)
            float a0 = bv[j], a1 = bv[j + 1];
            const float* Th = &Tls[wv][h][0];
#pragma unroll 4
            for (int k = 0; k < 96; ++k) {
                float t = Th[k];                   // wave-uniform: LDS broadcast
                float2 w = *(const float2*)&Wvs[k][j];  // 2-way alias: free
                a0 += t * w.x; a1 += t * w.y;
            }
            float2 o = (deg > 0) ? make_float2(a0, a1) : make_float2(0.f, 0.f);
            *(float2*)(agg + (long)node * 96 + j) = o;
        } else if (lane == 48) {
            cntF[node] = (float)deg;
        }
    }
}

// out = leaky_relu([x | agg | count] @ W_out + b_out)
// R11: coalesced float4 staging (transposed LDS writes); s_in padded to 68.
__global__ __launch_bounds__(256, 4)
void node_kernel(const float* __restrict__ x, const float* __restrict__ aggW,
                 const float* __restrict__ cntF,
                 const float* __restrict__ Wo, const float* __restrict__ bo,
                 float* __restrict__ out, int N)
{
    __shared__ float s_in[161][68];   // 272B rows: 16B-aligned float4 reads
    int n0 = blockIdx.x * 64;
    int j0 = blockIdx.y * 64;

    // x rows: 64 rows x 16 float4, lanes read consecutive float4s (coalesced)
    for (int idx = threadIdx.x; idx < 64 * 16; idx += 256) {
        int row = idx >> 4, f4 = idx & 15;
        int n = n0 + row;
        float4 v = make_float4(0.f, 0.f, 0.f, 0.f);
        if (n < N) v = ((const float4*)(x + (long)n * 64))[f4];
        s_in[4 * f4 + 0][row] = v.x; s_in[4 * f4 + 1][row] = v.y;
        s_in[4 * f4 + 2][row] = v.z; s_in[4 * f4 + 3][row] = v.w;
    }
    // agg rows: 64 rows x 24 float4, coalesced
    for (int idx = threadIdx.x; idx < 64 * 24; idx += 256) {
        int row = idx / 24, c4 = idx % 24;
        int n = n0 + row;
        float4 v = make_float4(0.f, 0.f, 0.f, 0.f);
        if (n < N) v = ((const float4*)(aggW + (long)n * 96))[c4];
        s_in[64 + 4 * c4 + 0][row] = v.x; s_in[64 + 4 * c4 + 1][row] = v.y;
        s_in[64 + 4 * c4 + 2][row] = v.z; s_in[64 + 4 * c4 + 3][row] = v.w;
    }
    if (threadIdx.x < 64) {
        int n = n0 + threadIdx.x;
        s_in[160][threadIdx.x] = (n < N) ? cntF[n] : 0.f;
    }
    __syncthreads();

    int tj = threadIdx.x & 15;
    int tn = threadIdx.x >> 4;
    float acc[4][4];
#pragma unroll
    for (int i = 0; i < 4; ++i)
#pragma unroll
        for (int c = 0; c < 4; ++c) acc[i][c] = 0.f;

    const float* Wcol = Wo + j0 + tj * 4;
    for (int k = 0; k < 161; ++k) {
        float4 w  = *(const float4*)(Wcol + (long)k * 128);
        float4 iv = *(const float4*)&s_in[k][tn * 4];
        acc[0][0] += iv.x * w.x; acc[0][1] += iv.x * w.y; acc[0][2] += iv.x * w.z; acc[0][3] += iv.x * w.w;
        acc[1][0] += iv.y * w.x; acc[1][1] += iv.y * w.y; acc[1][2] += iv.y * w.z; acc[1][3] += iv.y * w.w;
        acc[2][0] += iv.z * w.x; acc[2][1] += iv.z * w.y; acc[2][2] += iv.z * w.z; acc[2][3] += iv.z * w.w;
        acc[3][0] += iv.w * w.x; acc[3][1] += iv.w * w.y; acc[3][2] += iv.w * w.z; acc[3][3] += iv.w * w.w;
    }
    float4 b = *(const float4*)(bo + j0 + tj * 4);
#pragma unroll
    for (int i = 0; i < 4; ++i) {
        int n = n0 + tn * 4 + i;
        if (n < N) {
            float4 o;
            o.x = lrelu(acc[i][0] + b.x);
            o.y = lrelu(acc[i][1] + b.y);
            o.z = lrelu(acc[i][2] + b.z);
            o.w = lrelu(acc[i][3] + b.w);
            *(float4*)(out + (long)n * 128 + j0 + tj * 4) = o;
        }
    }
}

// ---------------- fallback (round-2 atomic path, used if ws too small) -----
__global__ __launch_bounds__(256, 1)
void edge_atm_kernel(const float* __restrict__ x, const float* __restrict__ ea,
                     const int* __restrict__ ei,
                     const float* __restrict__ Wp, const float* __restrict__ bp,
                     const float* __restrict__ Wa, const float* __restrict__ ba,
                     const float* __restrict__ Wv, const float* __restrict__ bv,
                     float* __restrict__ aggW, float* __restrict__ denomW,
                     float* __restrict__ cntW, int E)
{
    int e = blockIdx.x * 256 + threadIdx.x;
    if (e >= E) return;
    int src = ei[e];
    int dst = ei[E + e];
    float4 S[24];
#pragma unroll
    for (int j = 0; j < 24; ++j) S[j] = ((const float4*)bp)[j];
    const float* xrow = x + (long)src * 64;
    const float* erow = ea + (long)e * 32;
#pragma unroll 1
    for (int kc = 0; kc < 6; ++kc) {
        const float* sp = (kc < 4) ? (xrow + kc * 16) : (erow + (kc - 4) * 16);
        const float* Wb = Wp + kc * 16 * 96;
#pragma unroll 1
        for (int i = 0; i < 4; ++i) {
            float4 cc = ((const float4*)sp)[i];
#pragma unroll
            for (int j = 0; j < 24; ++j) {
                float4 w0 = ((const float4*)(Wb + (4 * i + 0) * 96))[j];
                float4 w1 = ((const float4*)(Wb + (4 * i + 1) * 96))[j];
                float4 w2 = ((const float4*)(Wb + (4 * i + 2) * 96))[j];
                float4 w3 = ((const float4*)(Wb + (4 * i + 3) * 96))[j];
                S[j].x += cc.x * w0.x + cc.y * w1.x + cc.z * w2.x + cc.w * w3.x;
                S[j].y += cc.x * w0.y + cc.y * w1.y + cc.z * w2.y + cc.w * w3.y;
                S[j].z += cc.x * w0.z + cc.y * w1.z + cc.z * w2.z + cc.w * w3.z;
                S[j].w += cc.x * w0.w + cc.y * w1.w + cc.z * w2.w + cc.w * w3.w;
            }
        }
    }
#pragma unroll
    for (int j = 0; j < 24; ++j) {
        S[j].x = lrelu(S[j].x); S[j].y = lrelu(S[j].y);
        S[j].z = lrelu(S[j].z); S[j].w = lrelu(S[j].w);
    }
    float l0 = ba[0], l1 = ba[1], l2 = ba[2], l3 = ba[3];
#pragma unroll
    for (int j = 0; j < 24; ++j) {
        float4 m = S[j];
        float4 w0 = ((const float4*)(Wa + (4 * j + 0) * 4))[0];
        float4 w1 = ((const float4*)(Wa + (4 * j + 1) * 4))[0];
        float4 w2 = ((const float4*)(Wa + (4 * j + 2) * 4))[0];
        float4 w3 = ((const float4*)(Wa + (4 * j + 3) * 4))[0];
        l0 += m.x * w0.x + m.y * w1.x + m.z * w2.x + m.w * w3.x;
        l1 += m.x * w0.y + m.y * w1.y + m.z * w2.y + m.w * w3.y;
        l2 += m.x * w0.z + m.y * w1.z + m.z * w2.z + m.w * w3.z;
        l3 += m.x * w0.w + m.y * w1.w + m.z * w2.w + m.w * w3.w;
    }
    float p0 = __expf(l0), p1 = __expf(l1), p2 = __expf(l2), p3 = __expf(l3);
    float* aggp = aggW + (long)dst * 96;
#pragma unroll 1
    for (int j4 = 0; j4 < 24; ++j4) {
        float4 acc = ((const float4*)bv)[j4];
        const float* Wc = Wv + 4 * j4;
#pragma unroll
        for (int j = 0; j < 24; ++j) {
            float4 m = S[j];
            float4 w0 = ((const float4*)(Wc + (4 * j + 0) * 96))[0];
            float4 w1 = ((const float4*)(Wc + (4 * j + 1) * 96))[0];
            float4 w2 = ((const float4*)(Wc + (4 * j + 2) * 96))[0];
            float4 w3 = ((const float4*)(Wc + (4 * j + 3) * 96))[0];
            acc.x += m.x * w0.x + m.y * w1.x + m.z * w2.x + m.w * w3.x;
            acc.y += m.x * w0.y + m.y * w1.y + m.z * w2.y + m.w * w3.y;
            acc.z += m.x * w0.z + m.y * w1.z + m.z * w2.z + m.w * w3.z;
            acc.w += m.x * w0.w + m.y * w1.w + m.z * w2.w + m.w * w3.w;
        }
        float ph = (j4 < 6) ? p0 : (j4 < 12) ? p1 : (j4 < 18) ? p2 : p3;
        unsafeAtomicAdd(aggp + 4 * j4 + 0, ph * acc.x);
        unsafeAtomicAdd(aggp + 4 * j4 + 1, ph * acc.y);
        unsafeAtomicAdd(aggp + 4 * j4 + 2, ph * acc.z);
        unsafeAtomicAdd(aggp + 4 * j4 + 3, ph * acc.w);
    }
    float* dn = denomW + (long)dst * 4;
    unsafeAtomicAdd(dn + 0, p0);
    unsafeAtomicAdd(dn + 1, p1);
    unsafeAtomicAdd(dn + 2, p2);
    unsafeAtomicAdd(dn + 3, p3);
    unsafeAtomicAdd(cntW + dst, 1.0f);
}

__global__ __launch_bounds__(256, 4)
void node_atm_kernel(const float* __restrict__ x, const float* __restrict__ aggW,
                     const float* __restrict__ denomW, const float* __restrict__ cntW,
                     const float* __restrict__ Wo, const float* __restrict__ bo,
                     float* __restrict__ out, int N)
{
    __shared__ float s_in[161][64];
    int n0 = blockIdx.x * 64;
    int j0 = blockIdx.y * 64;
    for (int p = threadIdx.x; p < 161 * 64; p += 256) {
        int k = p >> 6, nl = p & 63;
        int n = n0 + nl;
        float v = 0.f;
        if (n < N) {
            if (k < 64) v = x[(long)n * 64 + k];
            else if (k < 160) {
                int kk = k - 64;
                float d = denomW[n * 4 + (kk / 24)];
                v = d > 0.f ? aggW[(long)n * 96 + kk] / d : 0.f;
            } else v = cntW[n];
        }
        s_in[k][nl] = v;
    }
    __syncthreads();
    int tj = threadIdx.x & 15;
    int tn = threadIdx.x >> 4;
    float acc[4][4];
#pragma unroll
    for (int i = 0; i < 4; ++i)
#pragma unroll
        for (int c = 0; c < 4; ++c) acc[i][c] = 0.f;
    const float* Wcol = Wo + j0 + tj * 4;
    for (int k = 0; k < 161; ++k) {
        float4 w  = *(const float4*)(Wcol + (long)k * 128);
        float4 iv = *(const float4*)&s_in[k][tn * 4];
        acc[0][0] += iv.x * w.x; acc[0][1] += iv.x * w.y; acc[0][2] += iv.x * w.z; acc[0][3] += iv.x * w.w;
        acc[1][0] += iv.y * w.x; acc[1][1] += iv.y * w.y; acc[1][2] += iv.y * w.z; acc[1][3] += iv.y * w.w;
        acc[2][0] += iv.z * w.x; acc[2][1] += iv.z * w.y; acc[2][2] += iv.z * w.z; acc[2][3] += iv.z * w.w;
        acc[3][0] += iv.w * w.x; acc[3][1] += iv.w * w.y; acc[3][2] += iv.w * w.z; acc[3][3] += iv.w * w.w;
    }
    float4 b = *(const float4*)(bo + j0 + tj * 4);
#pragma unroll
    for (int i = 0; i < 4; ++i) {
        int n = n0 + tn * 4 + i;
        if (n < N) {
            float4 o;
            o.x = lrelu(acc[i][0] + b.x);
            o.y = lrelu(acc[i][1] + b.y);
            o.z = lrelu(acc[i][2] + b.z);
            o.w = lrelu(acc[i][3] + b.w);
            *(float4*)(out + (long)n * 128 + j0 + tj * 4) = o;
        }
    }
}

extern "C" void kernel_launch(void* const* d_in, const int* in_sizes, int n_in,
                              void* d_out, int out_size, void* d_ws, size_t ws_size,
                              hipStream_t stream)
{
    const float* x  = (const float*)d_in[0];
    const float* ea = (const float*)d_in[1];
    const int*   ei = (const int*)d_in[2];
    const float* Wp = (const float*)d_in[3];
    const float* bp = (const float*)d_in[4];
    const float* Wa = (const float*)d_in[5];
    const float* ba = (const float*)d_in[6];
    const float* Wv = (const float*)d_in[7];
    const float* bv = (const float*)d_in[8];
    const float* Wo = (const float*)d_in[9];
    const float* bo = (const float*)d_in[10];
    float* out = (float*)d_out;

    int N = in_sizes[0] / 64;
    int E = in_sizes[2] / 2;
    int NB = (N + 1023) / 1024;

    // vals | U/agg(alias) | cntF | cnti | offs | curs | bsum | eidx
    size_t need = (size_t)E * 52 * 4 + (size_t)N * 96 * 4 + (size_t)N * 4 * 4
                + (size_t)NB * 4 + (size_t)E * 4;

    if (ws_size >= need) {
        unsigned* vals = (unsigned*)d_ws;
        float* Uagg = (float*)(vals + (long)E * 52);   // U, later overwritten as agg
        float* cntF = Uagg + (long)N * 96;
        int*   cnti = (int*)(cntF + N);
        int*   offs = cnti + N;
        int*   curs = offs + N;
        int*   bsum = curs + N;
        int*   eidx = bsum + NB;

        hipMemsetAsync(cnti, 0, (size_t)N * sizeof(int), stream);
        hist_kernel<<<(E + 255) / 256, 256, 0, stream>>>(ei, cnti, E);
        if (NB <= 1024) {
            blocksum_kernel<<<NB, 256, 0, stream>>>(cnti, bsum, N);
            bscan_kernel<<<1, 1024, 0, stream>>>(bsum, NB);
            offs_kernel<<<NB, 1024, 0, stream>>>(cnti, bsum, offs, curs, N);
        } else {
            scan_kernel<<<1, 1024, 0, stream>>>(cnti, offs, curs, N);
        }
        pre_kernel<<<(N + 63) / 64, 256, 0, stream>>>(x, Wp, bp, Uagg, N);
        edge_msg_kernel<<<(2 * E + 255) / 256, 256, 0, stream>>>(
            Uagg, ea, ei, Wp, Wa, ba, vals, curs, eidx, E);
        gather_kernel<<<(N + 7) / 8, 512, 0, stream>>>(
            vals, offs, cnti, eidx, Wv, bv, Uagg, cntF, N);
        dim3 ng((N + 63) / 64, 2);
        node_kernel<<<ng, 256, 0, stream>>>(x, Uagg, cntF, Wo, bo, out, N);
    } else {
        float* aggW   = (float*)d_ws;
        float* denomW = aggW + (long)N * 96;
        float* cntW   = denomW + (long)N * 4;
        long zn = (long)N * 101;
        int  zb = (int)(((zn + 3) / 4 + 255) / 256);
        zero_kernel<<<zb, 256, 0, stream>>>(aggW, zn);
        edge_atm_kernel<<<(E + 255) / 256, 256, 0, stream>>>(
            x, ea, ei, Wp, bp, Wa, ba, Wv, bv, aggW, denomW, cntW, E);
        dim3 ng((N + 63) / 64, 2);
        node_atm_kernel<<<ng, 256, 0, stream>>>(x, aggW, denomW, cntW, Wo, bo, out, N);
    }
}

// Round 10
// 735.654 us; speedup vs baseline: 1.0202x; 1.0202x over previous
//
#include <hip/hip_runtime.h>

// MultiHeadAttentionConvIndex — round 16: coop ea staging in edge_msg.
// R13/R14/R15 all ~205us with no pipe >41% — bottleneck hypothesis: TA/L1
// request throughput (per-lane divergent loads: U 12x64-line, ea 8x64-line
// x2 waves duplicated, vals 13x64-line). This round removes the ea slice:
// pair cooperatively stages its 8KB of ea with coalesced float4 loads
// (16 lines/inst) into LDS[64][36]; both waves read rows from LDS (b128 at
// the 8-bank bandwidth floor). ~900 requests/pair saved; LDS 20.4KB -> 3
// blocks/CU (occupancy-neutral). A clean A/B of the request-bound theory.
//
// ws: vals[E*52 u32] | U/agg alias [N*96 f32] | cntF[N] | cnti[N] offs[N]
//     curs[N] | bsum[NB] | eidx[E]

#define NEG 0.01f

__device__ __forceinline__ float lrelu(float v) { return v > 0.f ? v : NEG * v; }

__device__ __forceinline__ unsigned bfpack2(float a, float b) {
    unsigned ua = __float_as_uint(a); ua = (ua + 0x7fff + ((ua >> 16) & 1)) >> 16;
    unsigned ub = __float_as_uint(b); ub = (ub + 0x7fff + ((ub >> 16) & 1)) >> 16;
    return ua | (ub << 16);
}

__global__ void zero_kernel(float* __restrict__ p, long n) {
    long i = ((long)blockIdx.x * 256 + threadIdx.x) * 4;
    if (i + 3 < n) {
        *(float4*)(p + i) = make_float4(0.f, 0.f, 0.f, 0.f);
    } else {
        for (long k = i; k < n; ++k) p[k] = 0.f;
    }
}

__global__ void hist_kernel(const int* __restrict__ ei, int* __restrict__ cnt, int E) {
    int e = blockIdx.x * 256 + threadIdx.x;
    if (e < E) atomicAdd(&cnt[ei[E + e]], 1);
}

// ---- fallback serial scan (used only if NB > 1024) ----
__global__ __launch_bounds__(1024)
void scan_kernel(const int* __restrict__ cnt, int* __restrict__ offs,
                 int* __restrict__ curs, int N) {
    __shared__ int ls[1024];
    int tid = threadIdx.x;
    int chunk = (N + 1023) >> 10;
    int lo = tid * chunk;
    int hi = lo + chunk; if (hi > N) hi = N; if (lo > N) lo = N;
    int s = 0;
    for (int i = lo; i < hi; ++i) s += cnt[i];
    ls[tid] = s;
    __syncthreads();
    for (int off = 1; off < 1024; off <<= 1) {
        int v = 0;
        if (tid >= off) v = ls[tid - off];
        __syncthreads();
        ls[tid] += v;
        __syncthreads();
    }
    int run = ls[tid] - s;
    for (int i = lo; i < hi; ++i) {
        offs[i] = run; curs[i] = run; run += cnt[i];
    }
}

// ---- parallel scan, phase 1: per-1024-chunk sums ----
__global__ __launch_bounds__(256)
void blocksum_kernel(const int* __restrict__ cnt, int* __restrict__ bsum, int N) {
    int base = blockIdx.x * 1024;
    int tid = threadIdx.x;
    int v = 0;
#pragma unroll
    for (int r = 0; r < 4; ++r) {
        int idx = base + r * 256 + tid;
        if (idx < N) v += cnt[idx];
    }
#pragma unroll
    for (int d = 32; d > 0; d >>= 1) v += __shfl_down(v, d, 64);
    __shared__ int ws[4];
    int wv = tid >> 6, lane = tid & 63;
    if (lane == 0) ws[wv] = v;
    __syncthreads();
    if (tid == 0) bsum[blockIdx.x] = ws[0] + ws[1] + ws[2] + ws[3];
}

// ---- phase 2: exclusive scan of NB (<=1024) block sums, in place ----
__global__ __launch_bounds__(1024)
void bscan_kernel(int* __restrict__ bsum, int NB) {
    __shared__ int ls[1024];
    int tid = threadIdx.x;
    int v = (tid < NB) ? bsum[tid] : 0;
    ls[tid] = v;
    __syncthreads();
    for (int off = 1; off < 1024; off <<= 1) {
        int t = 0;
        if (tid >= off) t = ls[tid - off];
        __syncthreads();
        ls[tid] += t;
        __syncthreads();
    }
    if (tid < NB) bsum[tid] = ls[tid] - v;   // exclusive
}

// ---- phase 3: block-local scan + block offset -> offs/curs ----
__global__ __launch_bounds__(1024)
void offs_kernel(const int* __restrict__ cnt, const int* __restrict__ boff,
                 int* __restrict__ offs, int* __restrict__ curs, int N) {
    int tid = threadIdx.x;
    int i = blockIdx.x * 1024 + tid;
    int lane = tid & 63, wv = tid >> 6;
    int c = (i < N) ? cnt[i] : 0;
    int v = c;
#pragma unroll
    for (int d = 1; d < 64; d <<= 1) {
        int t = __shfl_up(v, d, 64);
        if (lane >= d) v += t;
    }
    __shared__ int ws[16];
    if (lane == 63) ws[wv] = v;
    __syncthreads();
    if (wv == 0) {
        int wvv = (lane < 16) ? ws[lane] : 0;
#pragma unroll
        for (int d = 1; d < 16; d <<= 1) {
            int t = __shfl_up(wvv, d, 64);
            if (lane >= d) wvv += t;
        }
        if (lane < 16) ws[lane] = wvv;       // inclusive wave sums
    }
    __syncthreads();
    int waveoff = (wv > 0) ? ws[wv - 1] : 0;
    int excl = v - c + waveoff + boff[blockIdx.x];
    if (i < N) { offs[i] = excl; curs[i] = excl; }
}

// U = x @ Wp[0:64,:] + bp   ([N,64]@[64,96], dense)
// 64 nodes/block; thread = (node, 24-col group).
__global__ __launch_bounds__(256, 4)
void pre_kernel(const float* __restrict__ x, const float* __restrict__ Wp,
                const float* __restrict__ bp, float* __restrict__ U, int N)
{
    __shared__ float xs[64][65];
    int n0 = blockIdx.x * 64;
    for (int p = threadIdx.x; p < 64 * 16; p += 256) {
        int row = p >> 4, f4 = p & 15;
        int n = n0 + row;
        float4 v = make_float4(0.f, 0.f, 0.f, 0.f);
        if (n < N) v = ((const float4*)(x + (long)n * 64))[f4];
        xs[row][f4 * 4 + 0] = v.x; xs[row][f4 * 4 + 1] = v.y;
        xs[row][f4 * 4 + 2] = v.z; xs[row][f4 * 4 + 3] = v.w;
    }
    __syncthreads();

    int node = threadIdx.x >> 2;
    int cg = threadIdx.x & 3;           // 4 col-groups of 24
    float4 acc[6];
#pragma unroll
    for (int c = 0; c < 6; ++c) acc[c] = ((const float4*)(bp + cg * 24))[c];
    for (int k = 0; k < 64; ++k) {
        float xv = xs[node][k];
        const float* wr = Wp + k * 96 + cg * 24;
#pragma unroll
        for (int c = 0; c < 6; ++c) {
            float4 w = ((const float4*)wr)[c];
            acc[c].x += xv * w.x; acc[c].y += xv * w.y;
            acc[c].z += xv * w.z; acc[c].w += xv * w.w;
        }
    }
    int n = n0 + node;
    if (n < N) {
#pragma unroll
        for (int c = 0; c < 6; ++c)
            ((float4*)(U + (long)n * 96 + cg * 24))[c] = acc[c];
    }
}

// Wave-half per edge: block = 4 waves = 2 pairs; pair covers 64 edges.
// wave half=0: cols 0-47 + CSR eidx fill; half=1: cols 48-95 + p store.
// ea staged cooperatively per pair (coalesced global -> LDS); weights scalar.
__global__ __launch_bounds__(256, 1)
void edge_msg_kernel(const float* __restrict__ U, const float* __restrict__ ea,
                     const int* __restrict__ ei,
                     const float* __restrict__ Wp,
                     const float* __restrict__ Wa, const float* __restrict__ ba,
                     unsigned* __restrict__ vals, int* __restrict__ curs,
                     int* __restrict__ eidx, int E)
{
    __shared__ __attribute__((aligned(16))) float eas[2][64][36];  // 18 KB
    __shared__ float ex[4][2][64];                                 // 2 KB

    int lane = threadIdx.x & 63;
    int wid  = threadIdx.x >> 6;                                  // 0..3
    int half = __builtin_amdgcn_readfirstlane(wid & 1);           // SGPR
    int pl   = __builtin_amdgcn_readfirstlane(wid >> 1);          // pair 0/1
    long pairBase = ((long)blockIdx.x * 2 + pl) * 64;
    int e = (int)(pairBase + lane);
    bool active = (e < E);
    int ec = active ? e : (E - 1);
    int src = ei[ec];
    int dst = ei[E + ec];

    // coop ea stage: pair's 8KB = 512 float4 over the pair's 128 threads.
    {
        const float4* gea = (const float4*)ea;
        long g0 = pairBase * 8;               // float4 index of pair base
        long gmax = (long)E * 8;
        int pt = (wid & 1) * 64 + lane;       // 0..127 within pair
#pragma unroll
        for (int i = 0; i < 4; ++i) {
            int idx = i * 128 + pt;           // 0..511
            long gi = g0 + idx;
            float4 v = make_float4(0.f, 0.f, 0.f, 0.f);
            if (gi < gmax) v = gea[gi];
            int ed = idx >> 3, f4 = idx & 7;
            *(float4*)&eas[pl][ed][f4 * 4] = v;
        }
    }

    // CSR permutation fill (even wave): latency hides under barrier+GEMM
    if (half == 0 && active) {
        int pos = atomicAdd(&curs[dst], 1);
        eidx[pos] = e;
    }
    __syncthreads();   // eas ready (each pair staged its own)

    float4 S[12];
    const float4* Urow = (const float4*)(U + (long)src * 96 + half * 48);
#pragma unroll
    for (int j = 0; j < 12; ++j) S[j] = Urow[j];

    const float* Wh = Wp + 64 * 96 + half * 48;   // scalar base

#pragma unroll 1
    for (int kc = 0; kc < 8; ++kc) {              // 8 chunks of 4 edge feats
        float4 c = *(const float4*)&eas[pl][lane][kc * 4];
        const float* W0 = Wh + (4 * kc + 0) * 96;
        const float* W1 = Wh + (4 * kc + 1) * 96;
        const float* W2 = Wh + (4 * kc + 2) * 96;
        const float* W3 = Wh + (4 * kc + 3) * 96;
#pragma unroll
        for (int j = 0; j < 12; ++j) {
            float4 w0 = ((const float4*)W0)[j];   // wave-uniform -> s_load
            float4 w1 = ((const float4*)W1)[j];
            float4 w2 = ((const float4*)W2)[j];
            float4 w3 = ((const float4*)W3)[j];
            S[j].x += c.x * w0.x + c.y * w1.x + c.z * w2.x + c.w * w3.x;
            S[j].y += c.x * w0.y + c.y * w1.y + c.z * w2.y + c.w * w3.y;
            S[j].z += c.x * w0.z + c.y * w1.z + c.z * w2.z + c.w * w3.z;
            S[j].w += c.x * w0.w + c.y * w1.w + c.z * w2.w + c.w * w3.w;
        }
    }
#pragma unroll
    for (int j = 0; j < 12; ++j) {
        S[j].x = lrelu(S[j].x); S[j].y = lrelu(S[j].y);
        S[j].z = lrelu(S[j].z); S[j].w = lrelu(S[j].w);
    }

    // partial logits over this half's 48 cols (Wa rows wave-uniform -> s_load)
    float l0 = 0.f, l1 = 0.f, l2 = 0.f, l3 = 0.f;
    const float* Wah = Wa + half * 48 * 4;
#pragma unroll
    for (int j = 0; j < 12; ++j) {
        float4 m = S[j];
        float4 w0 = ((const float4*)(Wah + (4 * j + 0) * 4))[0];
        float4 w1 = ((const float4*)(Wah + (4 * j + 1) * 4))[0];
        float4 w2 = ((const float4*)(Wah + (4 * j + 2) * 4))[0];
        float4 w3 = ((const float4*)(Wah + (4 * j + 3) * 4))[0];
        l0 += m.x * w0.x + m.y * w1.x + m.z * w2.x + m.w * w3.x;
        l1 += m.x * w0.y + m.y * w1.y + m.z * w2.y + m.w * w3.y;
        l2 += m.x * w0.z + m.y * w1.z + m.z * w2.z + m.w * w3.z;
        l3 += m.x * w0.w + m.y * w1.w + m.z * w2.w + m.w * w3.w;
    }

    // pair exchange: even wave publishes partial logits
    if (half == 0) {
        ex[0][pl][lane] = l0; ex[1][pl][lane] = l1;
        ex[2][pl][lane] = l2; ex[3][pl][lane] = l3;
    }
    __syncthreads();
    if (half == 1) {
        l0 += ex[0][pl][lane]; l1 += ex[1][pl][lane];
        l2 += ex[2][pl][lane]; l3 += ex[3][pl][lane];
    }

    if (active) {
        unsigned* rowb = vals + (long)e * 52;     // edge-order: dense span
        unsigned* row = rowb + half * 24;
#pragma unroll
        for (int j2 = 0; j2 < 6; ++j2) {          // 6 x dwordx4 per half
            uint4 u;
            u.x = bfpack2(S[2 * j2].x,     S[2 * j2].y);
            u.y = bfpack2(S[2 * j2].z,     S[2 * j2].w);
            u.z = bfpack2(S[2 * j2 + 1].x, S[2 * j2 + 1].y);
            u.w = bfpack2(S[2 * j2 + 1].z, S[2 * j2 + 1].w);
            ((uint4*)row)[j2] = u;
        }
        if (half == 1) {
            float p0 = __expf(l0 + ba[0]), p1 = __expf(l1 + ba[1]);
            float p2 = __expf(l2 + ba[2]), p3 = __expf(l3 + ba[3]);
            ((uint4*)rowb)[12] = make_uint4(__float_as_uint(p0), __float_as_uint(p1),
                                            __float_as_uint(p2), __float_as_uint(p3));
        }
    }
}

// One wave per node: T_h = sum_e p_h*msg_e; then agg = (T_h/sum p_h)@Wv + bv.
// Rows located via eidx[slot] indirection (vals stored in edge order).
// Shfl sources 48..51 are active inside the lane<52 scope (R3 lesson).
__global__ __launch_bounds__(512)
void gather_kernel(const unsigned* __restrict__ vals, const int* __restrict__ offs,
                   const int* __restrict__ cnt, const int* __restrict__ eidx,
                   const float* __restrict__ Wv, const float* __restrict__ bv,
                   float* __restrict__ agg, float* __restrict__ cntF, int N)
{
    __shared__ __attribute__((aligned(16))) float Wvs[96][96];  // 36 KB
    __shared__ float Tls[8][4][96];                             // 12 KB
    int wv = threadIdx.x >> 6;
    int lane = threadIdx.x & 63;
    int node = blockIdx.x * 8 + wv;
    bool nvalid = (node < N);

    // cooperative Wv stage: 2304 float4s over 512 threads
    for (int i = threadIdx.x; i < 96 * 24; i += 512)
        ((float4*)Wvs)[i] = ((const float4*)Wv)[i];
    __syncthreads();   // no early returns above: all 8 waves arrive

    int start = nvalid ? offs[node] : 0;
    int deg   = nvalid ? cnt[node] : 0;

    float s0[4] = {0.f, 0.f, 0.f, 0.f};
    float s1[4] = {0.f, 0.f, 0.f, 0.f};
    float d0 = 0.f, d1 = 0.f, d2 = 0.f, d3 = 0.f;
    if (lane < 52) {
        // Lanes 48..51 accumulate garbage (their own p-bits as "msg"), but
        // never store it — keeping them in removes per-row exec-mask flips.
#define PROC(v) {                                                   \
        float vf = __uint_as_float(v);                              \
        float q0 = __shfl(vf, 48, 64);                              \
        float q1 = __shfl(vf, 49, 64);                              \
        float q2 = __shfl(vf, 50, 64);                              \
        float q3 = __shfl(vf, 51, 64);                              \
        float m0 = __uint_as_float((v) << 16);                      \
        float m1 = __uint_as_float((v) & 0xffff0000u);              \
        s0[0] += q0 * m0; s1[0] += q0 * m1;                         \
        s0[1] += q1 * m0; s1[1] += q1 * m1;                         \
        s0[2] += q2 * m0; s1[2] += q2 * m1;                         \
        s0[3] += q3 * m0; s1[3] += q3 * m1;                         \
        d0 += q0; d1 += q1; d2 += q2; d3 += q3; }
        const int* eix = eidx + start;
        int r = 0;
        for (; r + 4 <= deg; r += 4) {           // 4 row loads in flight
            long o0 = (long)eix[r]     * 52;
            long o1 = (long)eix[r + 1] * 52;
            long o2 = (long)eix[r + 2] * 52;
            long o3 = (long)eix[r + 3] * 52;
            unsigned va = vals[o0 + lane];
            unsigned vb = vals[o1 + lane];
            unsigned vc = vals[o2 + lane];
            unsigned vd = vals[o3 + lane];
            PROC(va) PROC(vb) PROC(vc) PROC(vd)
        }
        for (; r < deg; ++r) {
            unsigned v = vals[(long)eix[r] * 52 + lane];
            PROC(v)
        }
#undef PROC
    }
    if (lane < 48) {
        float r0 = (deg > 0) ? 1.f / d0 : 0.f;
        float r1 = (deg > 0) ? 1.f / d1 : 0.f;
        float r2 = (deg > 0) ? 1.f / d2 : 0.f;
        float r3 = (deg > 0) ? 1.f / d3 : 0.f;
        Tls[wv][0][2 * lane] = s0[0] * r0; Tls[wv][0][2 * lane + 1] = s1[0] * r0;
        Tls[wv][1][2 * lane] = s0[1] * r1; Tls[wv][1][2 * lane + 1] = s1[1] * r1;
        Tls[wv][2][2 * lane] = s0[2] * r2; Tls[wv][2][2 * lane + 1] = s1[2] * r2;
        Tls[wv][3][2 * lane] = s0[3] * r3; Tls[wv][3][2 * lane + 1] = s1[3] * r3;
    }
    // Same-wave LDS producer/consumer for Tls[wv]: lgkmcnt wait is
    // compiler-inserted; no block barrier needed. Wvs was barriered above.
    if (nvalid) {
        if (lane < 48) {
            int j = 2 * lane;                      // output cols j, j+1
            int h = lane / 12;                     // head (pairs never straddle)
            float a0 = bv[j], a1 = bv[j + 1];
            const float* Th = &Tls[wv][h][0];
#pragma unroll 4
            for (int k = 0; k < 96; ++k) {
                float t = Th[k];                   // wave-uniform: LDS broadcast
                float2 w = *(const float2*)&Wvs[k][j];  // 2-way alias: free
                a0 += t * w.x; a1 += t * w.y;
            }
            float2 o = (deg > 0) ? make_float2(a0, a1) : make_float2(0.f, 0.f);
            *(float2*)(agg + (long)node * 96 + j) = o;
        } else if (lane == 48) {
            cntF[node] = (float)deg;
        }
    }
}

// out = leaky_relu([x | agg | count] @ W_out + b_out)
// R11: coalesced float4 staging (transposed LDS writes); s_in padded to 68.
__global__ __launch_bounds__(256, 4)
void node_kernel(const float* __restrict__ x, const float* __restrict__ aggW,
                 const float* __restrict__ cntF,
                 const float* __restrict__ Wo, const float* __restrict__ bo,
                 float* __restrict__ out, int N)
{
    __shared__ float s_in[161][68];   // 272B rows: 16B-aligned float4 reads
    int n0 = blockIdx.x * 64;
    int j0 = blockIdx.y * 64;

    // x rows: 64 rows x 16 float4, lanes read consecutive float4s (coalesced)
    for (int idx = threadIdx.x; idx < 64 * 16; idx += 256) {
        int row = idx >> 4, f4 = idx & 15;
        int n = n0 + row;
        float4 v = make_float4(0.f, 0.f, 0.f, 0.f);
        if (n < N) v = ((const float4*)(x + (long)n * 64))[f4];
        s_in[4 * f4 + 0][row] = v.x; s_in[4 * f4 + 1][row] = v.y;
        s_in[4 * f4 + 2][row] = v.z; s_in[4 * f4 + 3][row] = v.w;
    }
    // agg rows: 64 rows x 24 float4, coalesced
    for (int idx = threadIdx.x; idx < 64 * 24; idx += 256) {
        int row = idx / 24, c4 = idx % 24;
        int n = n0 + row;
        float4 v = make_float4(0.f, 0.f, 0.f, 0.f);
        if (n < N) v = ((const float4*)(aggW + (long)n * 96))[c4];
        s_in[64 + 4 * c4 + 0][row] = v.x; s_in[64 + 4 * c4 + 1][row] = v.y;
        s_in[64 + 4 * c4 + 2][row] = v.z; s_in[64 + 4 * c4 + 3][row] = v.w;
    }
    if (threadIdx.x < 64) {
        int n = n0 + threadIdx.x;
        s_in[160][threadIdx.x] = (n < N) ? cntF[n] : 0.f;
    }
    __syncthreads();

    int tj = threadIdx.x & 15;
    int tn = threadIdx.x >> 4;
    float acc[4][4];
#pragma unroll
    for (int i = 0; i < 4; ++i)
#pragma unroll
        for (int c = 0; c < 4; ++c) acc[i][c] = 0.f;

    const float* Wcol = Wo + j0 + tj * 4;
    for (int k = 0; k < 161; ++k) {
        float4 w  = *(const float4*)(Wcol + (long)k * 128);
        float4 iv = *(const float4*)&s_in[k][tn * 4];
        acc[0][0] += iv.x * w.x; acc[0][1] += iv.x * w.y; acc[0][2] += iv.x * w.z; acc[0][3] += iv.x * w.w;
        acc[1][0] += iv.y * w.x; acc[1][1] += iv.y * w.y; acc[1][2] += iv.y * w.z; acc[1][3] += iv.y * w.w;
        acc[2][0] += iv.z * w.x; acc[2][1] += iv.z * w.y; acc[2][2] += iv.z * w.z; acc[2][3] += iv.z * w.w;
        acc[3][0] += iv.w * w.x; acc[3][1] += iv.w * w.y; acc[3][2] += iv.w * w.z; acc[3][3] += iv.w * w.w;
    }
    float4 b = *(const float4*)(bo + j0 + tj * 4);
#pragma unroll
    for (int i = 0; i < 4; ++i) {
        int n = n0 + tn * 4 + i;
        if (n < N) {
            float4 o;
            o.x = lrelu(acc[i][0] + b.x);
            o.y = lrelu(acc[i][1] + b.y);
            o.z = lrelu(acc[i][2] + b.z);
            o.w = lrelu(acc[i][3] + b.w);
            *(float4*)(out + (long)n * 128 + j0 + tj * 4) = o;
        }
    }
}

// ---------------- fallback (round-2 atomic path, used if ws too small) -----
__global__ __launch_bounds__(256, 1)
void edge_atm_kernel(const float* __restrict__ x, const float* __restrict__ ea,
                     const int* __restrict__ ei,
                     const float* __restrict__ Wp, const float* __restrict__ bp,
                     const float* __restrict__ Wa, const float* __restrict__ ba,
                     const float* __restrict__ Wv, const float* __restrict__ bv,
                     float* __restrict__ aggW, float* __restrict__ denomW,
                     float* __restrict__ cntW, int E)
{
    int e = blockIdx.x * 256 + threadIdx.x;
    if (e >= E) return;
    int src = ei[e];
    int dst = ei[E + e];
    float4 S[24];
#pragma unroll
    for (int j = 0; j < 24; ++j) S[j] = ((const float4*)bp)[j];
    const float* xrow = x + (long)src * 64;
    const float* erow = ea + (long)e * 32;
#pragma unroll 1
    for (int kc = 0; kc < 6; ++kc) {
        const float* sp = (kc < 4) ? (xrow + kc * 16) : (erow + (kc - 4) * 16);
        const float* Wb = Wp + kc * 16 * 96;
#pragma unroll 1
        for (int i = 0; i < 4; ++i) {
            float4 cc = ((const float4*)sp)[i];
#pragma unroll
            for (int j = 0; j < 24; ++j) {
                float4 w0 = ((const float4*)(Wb + (4 * i + 0) * 96))[j];
                float4 w1 = ((const float4*)(Wb + (4 * i + 1) * 96))[j];
                float4 w2 = ((const float4*)(Wb + (4 * i + 2) * 96))[j];
                float4 w3 = ((const float4*)(Wb + (4 * i + 3) * 96))[j];
                S[j].x += cc.x * w0.x + cc.y * w1.x + cc.z * w2.x + cc.w * w3.x;
                S[j].y += cc.x * w0.y + cc.y * w1.y + cc.z * w2.y + cc.w * w3.y;
                S[j].z += cc.x * w0.z + cc.y * w1.z + cc.z * w2.z + cc.w * w3.z;
                S[j].w += cc.x * w0.w + cc.y * w1.w + cc.z * w2.w + cc.w * w3.w;
            }
        }
    }
#pragma unroll
    for (int j = 0; j < 24; ++j) {
        S[j].x = lrelu(S[j].x); S[j].y = lrelu(S[j].y);
        S[j].z = lrelu(S[j].z); S[j].w = lrelu(S[j].w);
    }
    float l0 = ba[0], l1 = ba[1], l2 = ba[2], l3 = ba[3];
#pragma unroll
    for (int j = 0; j < 24; ++j) {
        float4 m = S[j];
        float4 w0 = ((const float4*)(Wa + (4 * j + 0) * 4))[0];
        float4 w1 = ((const float4*)(Wa + (4 * j + 1) * 4))[0];
        float4 w2 = ((const float4*)(Wa + (4 * j + 2) * 4))[0];
        float4 w3 = ((const float4*)(Wa + (4 * j + 3) * 4))[0];
        l0 += m.x * w0.x + m.y * w1.x + m.z * w2.x + m.w * w3.x;
        l1 += m.x * w0.y + m.y * w1.y + m.z * w2.y + m.w * w3.y;
        l2 += m.x * w0.z + m.y * w1.z + m.z * w2.z + m.w * w3.z;
        l3 += m.x * w0.w + m.y * w1.w + m.z * w2.w + m.w * w3.w;
    }
    float p0 = __expf(l0), p1 = __expf(l1), p2 = __expf(l2), p3 = __expf(l3);
    float* aggp = aggW + (long)dst * 96;
#pragma unroll 1
    for (int j4 = 0; j4 < 24; ++j4) {
        float4 acc = ((const float4*)bv)[j4];
        const float* Wc = Wv + 4 * j4;
#pragma unroll
        for (int j = 0; j < 24; ++j) {
            float4 m = S[j];
            float4 w0 = ((const float4*)(Wc + (4 * j + 0) * 96))[0];
            float4 w1 = ((const float4*)(Wc + (4 * j + 1) * 96))[0];
            float4 w2 = ((const float4*)(Wc + (4 * j + 2) * 96))[0];
            float4 w3 = ((const float4*)(Wc + (4 * j + 3) * 96))[0];
            acc.x += m.x * w0.x + m.y * w1.x + m.z * w2.x + m.w * w3.x;
            acc.y += m.x * w0.y + m.y * w1.y + m.z * w2.y + m.w * w3.y;
            acc.z += m.x * w0.z + m.y * w1.z + m.z * w2.z + m.w * w3.z;
            acc.w += m.x * w0.w + m.y * w1.w + m.z * w2.w + m.w * w3.w;
        }
        float ph = (j4 < 6) ? p0 : (j4 < 12) ? p1 : (j4 < 18) ? p2 : p3;
        unsafeAtomicAdd(aggp + 4 * j4 + 0, ph * acc.x);
        unsafeAtomicAdd(aggp + 4 * j4 + 1, ph * acc.y);
        unsafeAtomicAdd(aggp + 4 * j4 + 2, ph * acc.z);
        unsafeAtomicAdd(aggp + 4 * j4 + 3, ph * acc.w);
    }
    float* dn = denomW + (long)dst * 4;
    unsafeAtomicAdd(dn + 0, p0);
    unsafeAtomicAdd(dn + 1, p1);
    unsafeAtomicAdd(dn + 2, p2);
    unsafeAtomicAdd(dn + 3, p3);
    unsafeAtomicAdd(cntW + dst, 1.0f);
}

__global__ __launch_bounds__(256, 4)
void node_atm_kernel(const float* __restrict__ x, const float* __restrict__ aggW,
                     const float* __restrict__ denomW, const float* __restrict__ cntW,
                     const float* __restrict__ Wo, const float* __restrict__ bo,
                     float* __restrict__ out, int N)
{
    __shared__ float s_in[161][64];
    int n0 = blockIdx.x * 64;
    int j0 = blockIdx.y * 64;
    for (int p = threadIdx.x; p < 161 * 64; p += 256) {
        int k = p >> 6, nl = p & 63;
        int n = n0 + nl;
        float v = 0.f;
        if (n < N) {
            if (k < 64) v = x[(long)n * 64 + k];
            else if (k < 160) {
                int kk = k - 64;
                float d = denomW[n * 4 + (kk / 24)];
                v = d > 0.f ? aggW[(long)n * 96 + kk] / d : 0.f;
            } else v = cntW[n];
        }
        s_in[k][nl] = v;
    }
    __syncthreads();
    int tj = threadIdx.x & 15;
    int tn = threadIdx.x >> 4;
    float acc[4][4];
#pragma unroll
    for (int i = 0; i < 4; ++i)
#pragma unroll
        for (int c = 0; c < 4; ++c) acc[i][c] = 0.f;
    const float* Wcol = Wo + j0 + tj * 4;
    for (int k = 0; k < 161; ++k) {
        float4 w  = *(const float4*)(Wcol + (long)k * 128);
        float4 iv = *(const float4*)&s_in[k][tn * 4];
        acc[0][0] += iv.x * w.x; acc[0][1] += iv.x * w.y; acc[0][2] += iv.x * w.z; acc[0][3] += iv.x * w.w;
        acc[1][0] += iv.y * w.x; acc[1][1] += iv.y * w.y; acc[1][2] += iv.y * w.z; acc[1][3] += iv.y * w.w;
        acc[2][0] += iv.z * w.x; acc[2][1] += iv.z * w.y; acc[2][2] += iv.z * w.z; acc[2][3] += iv.z * w.w;
        acc[3][0] += iv.w * w.x; acc[3][1] += iv.w * w.y; acc[3][2] += iv.w * w.z; acc[3][3] += iv.w * w.w;
    }
    float4 b = *(const float4*)(bo + j0 + tj * 4);
#pragma unroll
    for (int i = 0; i < 4; ++i) {
        int n = n0 + tn * 4 + i;
        if (n < N) {
            float4 o;
            o.x = lrelu(acc[i][0] + b.x);
            o.y = lrelu(acc[i][1] + b.y);
            o.z = lrelu(acc[i][2] + b.z);
            o.w = lrelu(acc[i][3] + b.w);
            *(float4*)(out + (long)n * 128 + j0 + tj * 4) = o;
        }
    }
}

extern "C" void kernel_launch(void* const* d_in, const int* in_sizes, int n_in,
                              void* d_out, int out_size, void* d_ws, size_t ws_size,
                              hipStream_t stream)
{
    const float* x  = (const float*)d_in[0];
    const float* ea = (const float*)d_in[1];
    const int*   ei = (const int*)d_in[2];
    const float* Wp = (const float*)d_in[3];
    const float* bp = (const float*)d_in[4];
    const float* Wa = (const float*)d_in[5];
    const float* ba = (const float*)d_in[6];
    const float* Wv = (const float*)d_in[7];
    const float* bv = (const float*)d_in[8];
    const float* Wo = (const float*)d_in[9];
    const float* bo = (const float*)d_in[10];
    float* out = (float*)d_out;

    int N = in_sizes[0] / 64;
    int E = in_sizes[2] / 2;
    int NB = (N + 1023) / 1024;

    // vals | U/agg(alias) | cntF | cnti | offs | curs | bsum | eidx
    size_t need = (size_t)E * 52 * 4 + (size_t)N * 96 * 4 + (size_t)N * 4 * 4
                + (size_t)NB * 4 + (size_t)E * 4;

    if (ws_size >= need) {
        unsigned* vals = (unsigned*)d_ws;
        float* Uagg = (float*)(vals + (long)E * 52);   // U, later overwritten as agg
        float* cntF = Uagg + (long)N * 96;
        int*   cnti = (int*)(cntF + N);
        int*   offs = cnti + N;
        int*   curs = offs + N;
        int*   bsum = curs + N;
        int*   eidx = bsum + NB;

        hipMemsetAsync(cnti, 0, (size_t)N * sizeof(int), stream);
        hist_kernel<<<(E + 255) / 256, 256, 0, stream>>>(ei, cnti, E);
        if (NB <= 1024) {
            blocksum_kernel<<<NB, 256, 0, stream>>>(cnti, bsum, N);
            bscan_kernel<<<1, 1024, 0, stream>>>(bsum, NB);
            offs_kernel<<<NB, 1024, 0, stream>>>(cnti, bsum, offs, curs, N);
        } else {
            scan_kernel<<<1, 1024, 0, stream>>>(cnti, offs, curs, N);
        }
        pre_kernel<<<(N + 63) / 64, 256, 0, stream>>>(x, Wp, bp, Uagg, N);
        edge_msg_kernel<<<(2 * E + 255) / 256, 256, 0, stream>>>(
            Uagg, ea, ei, Wp, Wa, ba, vals, curs, eidx, E);
        gather_kernel<<<(N + 7) / 8, 512, 0, stream>>>(
            vals, offs, cnti, eidx, Wv, bv, Uagg, cntF, N);
        dim3 ng((N + 63) / 64, 2);
        node_kernel<<<ng, 256, 0, stream>>>(x, Uagg, cntF, Wo, bo, out, N);
    } else {
        float* aggW   = (float*)d_ws;
        float* denomW = aggW + (long)N * 96;
        float* cntW   = denomW + (long)N * 4;
        long zn = (long)N * 101;
        int  zb = (int)(((zn + 3) / 4 + 255) / 256);
        zero_kernel<<<zb, 256, 0, stream>>>(aggW, zn);
        edge_atm_kernel<<<(E + 255) / 256, 256, 0, stream>>>(
            x, ea, ei, Wp, bp, Wa, ba, Wv, bv, aggW, denomW, cntW, E);
        dim3 ng((N + 63) / 64, 2);
        node_atm_kernel<<<ng, 256, 0, stream>>>(x, aggW, denomW, cntW, Wo, bo, out, N);
    }
}

// Round 12
// 717.855 us; speedup vs baseline: 1.0455x; 1.0248x over previous
//
#include <hip/hip_runtime.h>

// MultiHeadAttentionConvIndex — round 18: resubmit R17 (container failure,
// not a kernel verdict — no compile error / no passed:false / no profile).
// R17 theory: LDS-staged coalesced vals stores. R16 confirmed the
// TA-request theory (ea dedup: 203->188us, FETCH -34MB). Remaining
// divergent streams per pair: U 1536 reqs (random, irreducible), vals
// stores 1664 (208B/lane rows: 64 lines/inst + partial-line RMW).
// Fix: pack rows into a [64][52] u32 LDS image (b128 writes, ~8-way alias
// on idle LDS pipe), then coop-copy the pair's contiguous 13KB span with 7
// fully-coalesced uint4 insts (16 lines/inst). Pool reuses eas (dead after
// GEMM): max(18+2, 26.6)=26.6KB, occupancy unchanged. 4 barriers amortized
// over the 1536-FMA GEMM.
//
// ws: vals[E*52 u32] | U/agg alias [N*96 f32] | cntF[N] | cnti[N] offs[N]
//     curs[N] | bsum[NB] | eidx[E]

#define NEG 0.01f

__device__ __forceinline__ float lrelu(float v) { return v > 0.f ? v : NEG * v; }

__device__ __forceinline__ unsigned bfpack2(float a, float b) {
    unsigned ua = __float_as_uint(a); ua = (ua + 0x7fff + ((ua >> 16) & 1)) >> 16;
    unsigned ub = __float_as_uint(b); ub = (ub + 0x7fff + ((ub >> 16) & 1)) >> 16;
    return ua | (ub << 16);
}

__global__ void zero_kernel(float* __restrict__ p, long n) {
    long i = ((long)blockIdx.x * 256 + threadIdx.x) * 4;
    if (i + 3 < n) {
        *(float4*)(p + i) = make_float4(0.f, 0.f, 0.f, 0.f);
    } else {
        for (long k = i; k < n; ++k) p[k] = 0.f;
    }
}

__global__ void hist_kernel(const int* __restrict__ ei, int* __restrict__ cnt, int E) {
    int e = blockIdx.x * 256 + threadIdx.x;
    if (e < E) atomicAdd(&cnt[ei[E + e]], 1);
}

// ---- fallback serial scan (used only if NB > 1024) ----
__global__ __launch_bounds__(1024)
void scan_kernel(const int* __restrict__ cnt, int* __restrict__ offs,
                 int* __restrict__ curs, int N) {
    __shared__ int ls[1024];
    int tid = threadIdx.x;
    int chunk = (N + 1023) >> 10;
    int lo = tid * chunk;
    int hi = lo + chunk; if (hi > N) hi = N; if (lo > N) lo = N;
    int s = 0;
    for (int i = lo; i < hi; ++i) s += cnt[i];
    ls[tid] = s;
    __syncthreads();
    for (int off = 1; off < 1024; off <<= 1) {
        int v = 0;
        if (tid >= off) v = ls[tid - off];
        __syncthreads();
        ls[tid] += v;
        __syncthreads();
    }
    int run = ls[tid] - s;
    for (int i = lo; i < hi; ++i) {
        offs[i] = run; curs[i] = run; run += cnt[i];
    }
}

// ---- parallel scan, phase 1: per-1024-chunk sums ----
__global__ __launch_bounds__(256)
void blocksum_kernel(const int* __restrict__ cnt, int* __restrict__ bsum, int N) {
    int base = blockIdx.x * 1024;
    int tid = threadIdx.x;
    int v = 0;
#pragma unroll
    for (int r = 0; r < 4; ++r) {
        int idx = base + r * 256 + tid;
        if (idx < N) v += cnt[idx];
    }
#pragma unroll
    for (int d = 32; d > 0; d >>= 1) v += __shfl_down(v, d, 64);
    __shared__ int ws[4];
    int wv = tid >> 6, lane = tid & 63;
    if (lane == 0) ws[wv] = v;
    __syncthreads();
    if (tid == 0) bsum[blockIdx.x] = ws[0] + ws[1] + ws[2] + ws[3];
}

// ---- phase 2: exclusive scan of NB (<=1024) block sums, in place ----
__global__ __launch_bounds__(1024)
void bscan_kernel(int* __restrict__ bsum, int NB) {
    __shared__ int ls[1024];
    int tid = threadIdx.x;
    int v = (tid < NB) ? bsum[tid] : 0;
    ls[tid] = v;
    __syncthreads();
    for (int off = 1; off < 1024; off <<= 1) {
        int t = 0;
        if (tid >= off) t = ls[tid - off];
        __syncthreads();
        ls[tid] += t;
        __syncthreads();
    }
    if (tid < NB) bsum[tid] = ls[tid] - v;   // exclusive
}

// ---- phase 3: block-local scan + block offset -> offs/curs ----
__global__ __launch_bounds__(1024)
void offs_kernel(const int* __restrict__ cnt, const int* __restrict__ boff,
                 int* __restrict__ offs, int* __restrict__ curs, int N) {
    int tid = threadIdx.x;
    int i = blockIdx.x * 1024 + tid;
    int lane = tid & 63, wv = tid >> 6;
    int c = (i < N) ? cnt[i] : 0;
    int v = c;
#pragma unroll
    for (int d = 1; d < 64; d <<= 1) {
        int t = __shfl_up(v, d, 64);
        if (lane >= d) v += t;
    }
    __shared__ int ws[16];
    if (lane == 63) ws[wv] = v;
    __syncthreads();
    if (wv == 0) {
        int wvv = (lane < 16) ? ws[lane] : 0;
#pragma unroll
        for (int d = 1; d < 16; d <<= 1) {
            int t = __shfl_up(wvv, d, 64);
            if (lane >= d) wvv += t;
        }
        if (lane < 16) ws[lane] = wvv;       // inclusive wave sums
    }
    __syncthreads();
    int waveoff = (wv > 0) ? ws[wv - 1] : 0;
    int excl = v - c + waveoff + boff[blockIdx.x];
    if (i < N) { offs[i] = excl; curs[i] = excl; }
}

// U = x @ Wp[0:64,:] + bp   ([N,64]@[64,96], dense)
// 64 nodes/block; thread = (node, 24-col group).
__global__ __launch_bounds__(256, 4)
void pre_kernel(const float* __restrict__ x, const float* __restrict__ Wp,
                const float* __restrict__ bp, float* __restrict__ U, int N)
{
    __shared__ float xs[64][65];
    int n0 = blockIdx.x * 64;
    for (int p = threadIdx.x; p < 64 * 16; p += 256) {
        int row = p >> 4, f4 = p & 15;
        int n = n0 + row;
        float4 v = make_float4(0.f, 0.f, 0.f, 0.f);
        if (n < N) v = ((const float4*)(x + (long)n * 64))[f4];
        xs[row][f4 * 4 + 0] = v.x; xs[row][f4 * 4 + 1] = v.y;
        xs[row][f4 * 4 + 2] = v.z; xs[row][f4 * 4 + 3] = v.w;
    }
    __syncthreads();

    int node = threadIdx.x >> 2;
    int cg = threadIdx.x & 3;           // 4 col-groups of 24
    float4 acc[6];
#pragma unroll
    for (int c = 0; c < 6; ++c) acc[c] = ((const float4*)(bp + cg * 24))[c];
    for (int k = 0; k < 64; ++k) {
        float xv = xs[node][k];
        const float* wr = Wp + k * 96 + cg * 24;
#pragma unroll
        for (int c = 0; c < 6; ++c) {
            float4 w = ((const float4*)wr)[c];
            acc[c].x += xv * w.x; acc[c].y += xv * w.y;
            acc[c].z += xv * w.z; acc[c].w += xv * w.w;
        }
    }
    int n = n0 + node;
    if (n < N) {
#pragma unroll
        for (int c = 0; c < 6; ++c)
            ((float4*)(U + (long)n * 96 + cg * 24))[c] = acc[c];
    }
}

// Wave-half per edge: block = 4 waves = 2 pairs; pair covers 64 edges.
// wave half=0: cols 0-47 + CSR eidx fill; half=1: cols 48-95 + p.
// ea staged cooperatively; output staged in LDS image, coop-copied out
// coalesced (pair's 13KB span is contiguous in edge-order layout).
__global__ __launch_bounds__(256, 1)
void edge_msg_kernel(const float* __restrict__ U, const float* __restrict__ ea,
                     const int* __restrict__ ei,
                     const float* __restrict__ Wp,
                     const float* __restrict__ Wa, const float* __restrict__ ba,
                     unsigned* __restrict__ vals, int* __restrict__ curs,
                     int* __restrict__ eidx, int E)
{
    // pool phases: A) eas[2][64][36] f32 (18KB) + ex[4][2][64] f32 (2KB)
    //              B) st[2][64][52] u32 (26.6KB) — after eas/ex are dead
    __shared__ __attribute__((aligned(16))) unsigned pool[2 * 64 * 52];
    float* easf = (float*)pool;            // 4608 floats
    float* exf  = (float*)pool + 4608;     // 512 floats

    int lane = threadIdx.x & 63;
    int wid  = threadIdx.x >> 6;                                  // 0..3
    int half = __builtin_amdgcn_readfirstlane(wid & 1);           // SGPR
    int pl   = __builtin_amdgcn_readfirstlane(wid >> 1);          // pair 0/1
    int pt   = (wid & 1) * 64 + lane;                             // 0..127 in pair
    long pairBase = ((long)blockIdx.x * 2 + pl) * 64;
    int e = (int)(pairBase + lane);
    bool active = (e < E);
    int ec = active ? e : (E - 1);
    int src = ei[ec];
    int dst = ei[E + ec];

    // coop ea stage: pair's 8KB = 512 float4 over the pair's 128 threads.
    {
        const float4* gea = (const float4*)ea;
        long g0 = pairBase * 8;               // float4 index of pair base
        long gmax = (long)E * 8;
#pragma unroll
        for (int i = 0; i < 4; ++i) {
            int idx = i * 128 + pt;           // 0..511
            long gi = g0 + idx;
            float4 v = make_float4(0.f, 0.f, 0.f, 0.f);
            if (gi < gmax) v = gea[gi];
            int ed = idx >> 3, f4 = idx & 7;
            *(float4*)(easf + ((pl * 64 + ed) * 36 + f4 * 4)) = v;
        }
    }

    // CSR permutation fill (even wave): latency hides under barrier+GEMM
    if (half == 0 && active) {
        int pos = atomicAdd(&curs[dst], 1);
        eidx[pos] = e;
    }
    __syncthreads();   // eas ready

    float4 S[12];
    const float4* Urow = (const float4*)(U + (long)src * 96 + half * 48);
#pragma unroll
    for (int j = 0; j < 12; ++j) S[j] = Urow[j];

    const float* Wh = Wp + 64 * 96 + half * 48;   // scalar base

#pragma unroll 1
    for (int kc = 0; kc < 8; ++kc) {              // 8 chunks of 4 edge feats
        float4 c = *(const float4*)(easf + ((pl * 64 + lane) * 36 + kc * 4));
        const float* W0 = Wh + (4 * kc + 0) * 96;
        const float* W1 = Wh + (4 * kc + 1) * 96;
        const float* W2 = Wh + (4 * kc + 2) * 96;
        const float* W3 = Wh + (4 * kc + 3) * 96;
#pragma unroll
        for (int j = 0; j < 12; ++j) {
            float4 w0 = ((const float4*)W0)[j];   // wave-uniform -> s_load
            float4 w1 = ((const float4*)W1)[j];
            float4 w2 = ((const float4*)W2)[j];
            float4 w3 = ((const float4*)W3)[j];
            S[j].x += c.x * w0.x + c.y * w1.x + c.z * w2.x + c.w * w3.x;
            S[j].y += c.x * w0.y + c.y * w1.y + c.z * w2.y + c.w * w3.y;
            S[j].z += c.x * w0.z + c.y * w1.z + c.z * w2.z + c.w * w3.z;
            S[j].w += c.x * w0.w + c.y * w1.w + c.z * w2.w + c.w * w3.w;
        }
    }
#pragma unroll
    for (int j = 0; j < 12; ++j) {
        S[j].x = lrelu(S[j].x); S[j].y = lrelu(S[j].y);
        S[j].z = lrelu(S[j].z); S[j].w = lrelu(S[j].w);
    }

    // partial logits over this half's 48 cols (Wa rows wave-uniform -> s_load)
    float l0 = 0.f, l1 = 0.f, l2 = 0.f, l3 = 0.f;
    const float* Wah = Wa + half * 48 * 4;
#pragma unroll
    for (int j = 0; j < 12; ++j) {
        float4 m = S[j];
        float4 w0 = ((const float4*)(Wah + (4 * j + 0) * 4))[0];
        float4 w1 = ((const float4*)(Wah + (4 * j + 1) * 4))[0];
        float4 w2 = ((const float4*)(Wah + (4 * j + 2) * 4))[0];
        float4 w3 = ((const float4*)(Wah + (4 * j + 3) * 4))[0];
        l0 += m.x * w0.x + m.y * w1.x + m.z * w2.x + m.w * w3.x;
        l1 += m.x * w0.y + m.y * w1.y + m.z * w2.y + m.w * w3.y;
        l2 += m.x * w0.z + m.y * w1.z + m.z * w2.z + m.w * w3.z;
        l3 += m.x * w0.w + m.y * w1.w + m.z * w2.w + m.w * w3.w;
    }

    // pair exchange: even wave publishes partial logits
    if (half == 0) {
        exf[0 * 128 + pl * 64 + lane] = l0;
        exf[1 * 128 + pl * 64 + lane] = l1;
        exf[2 * 128 + pl * 64 + lane] = l2;
        exf[3 * 128 + pl * 64 + lane] = l3;
    }
    __syncthreads();
    if (half == 1) {
        l0 += exf[0 * 128 + pl * 64 + lane];
        l1 += exf[1 * 128 + pl * 64 + lane];
        l2 += exf[2 * 128 + pl * 64 + lane];
        l3 += exf[3 * 128 + pl * 64 + lane];
    }
    __syncthreads();   // eas + ex consumed -> pool reusable as st

    // stage output rows into LDS image st[2][64][52]
    if (active) {
        unsigned* srow = pool + ((pl * 64 + lane) * 52) + half * 24;
#pragma unroll
        for (int j2 = 0; j2 < 6; ++j2) {
            uint4 u;
            u.x = bfpack2(S[2 * j2].x,     S[2 * j2].y);
            u.y = bfpack2(S[2 * j2].z,     S[2 * j2].w);
            u.z = bfpack2(S[2 * j2 + 1].x, S[2 * j2 + 1].y);
            u.w = bfpack2(S[2 * j2 + 1].z, S[2 * j2 + 1].w);
            *(uint4*)(srow + j2 * 4) = u;
        }
        if (half == 1) {
            float p0 = __expf(l0 + ba[0]), p1 = __expf(l1 + ba[1]);
            float p2 = __expf(l2 + ba[2]), p3 = __expf(l3 + ba[3]);
            *(uint4*)(pool + ((pl * 64 + lane) * 52) + 48) =
                make_uint4(__float_as_uint(p0), __float_as_uint(p1),
                           __float_as_uint(p2), __float_as_uint(p3));
        }
    }
    __syncthreads();   // st ready

    // coop copy: pair's contiguous 13KB span, fully coalesced uint4 stores
    {
        long nval = (long)E - pairBase;
        if (nval > 64) nval = 64;
        if (nval > 0) {
            int tot = (int)nval * 13;                    // uint4 count
            uint4* dst4 = (uint4*)(vals + pairBase * 52);
            const uint4* src4 = (const uint4*)(pool + pl * 64 * 52);
            for (int i = pt; i < tot; i += 128)
                dst4[i] = src4[i];
        }
    }
}

// One wave per node: T_h = sum_e p_h*msg_e; then agg = (T_h/sum p_h)@Wv + bv.
// Rows located via eidx[slot] indirection (vals stored in edge order).
// Shfl sources 48..51 are active inside the lane<52 scope (R3 lesson).
__global__ __launch_bounds__(512)
void gather_kernel(const unsigned* __restrict__ vals, const int* __restrict__ offs,
                   const int* __restrict__ cnt, const int* __restrict__ eidx,
                   const float* __restrict__ Wv, const float* __restrict__ bv,
                   float* __restrict__ agg, float* __restrict__ cntF, int N)
{
    __shared__ __attribute__((aligned(16))) float Wvs[96][96];  // 36 KB
    __shared__ float Tls[8][4][96];                             // 12 KB
    int wv = threadIdx.x >> 6;
    int lane = threadIdx.x & 63;
    int node = blockIdx.x * 8 + wv;
    bool nvalid = (node < N);

    // cooperative Wv stage: 2304 float4s over 512 threads
    for (int i = threadIdx.x; i < 96 * 24; i += 512)
        ((float4*)Wvs)[i] = ((const float4*)Wv)[i];
    __syncthreads();   // no early returns above: all 8 waves arrive

    int start = nvalid ? offs[node] : 0;
    int deg   = nvalid ? cnt[node] : 0;

    float s0[4] = {0.f, 0.f, 0.f, 0.f};
    float s1[4] = {0.f, 0.f, 0.f, 0.f};
    float d0 = 0.f, d1 = 0.f, d2 = 0.f, d3 = 0.f;
    if (lane < 52) {
        // Lanes 48..51 accumulate garbage (their own p-bits as "msg"), but
        // never store it — keeping them in removes per-row exec-mask flips.
#define PROC(v) {                                                   \
        float vf = __uint_as_float(v);                              \
        float q0 = __shfl(vf, 48, 64);                              \
        float q1 = __shfl(vf, 49, 64);                              \
        float q2 = __shfl(vf, 50, 64);                              \
        float q3 = __shfl(vf, 51, 64);                              \
        float m0 = __uint_as_float((v) << 16);                      \
        float m1 = __uint_as_float((v) & 0xffff0000u);              \
        s0[0] += q0 * m0; s1[0] += q0 * m1;                         \
        s0[1] += q1 * m0; s1[1] += q1 * m1;                         \
        s0[2] += q2 * m0; s1[2] += q2 * m1;                         \
        s0[3] += q3 * m0; s1[3] += q3 * m1;                         \
        d0 += q0; d1 += q1; d2 += q2; d3 += q3; }
        const int* eix = eidx + start;
        int r = 0;
        for (; r + 4 <= deg; r += 4) {           // 4 row loads in flight
            long o0 = (long)eix[r]     * 52;
            long o1 = (long)eix[r + 1] * 52;
            long o2 = (long)eix[r + 2] * 52;
            long o3 = (long)eix[r + 3] * 52;
            unsigned va = vals[o0 + lane];
            unsigned vb = vals[o1 + lane];
            unsigned vc = vals[o2 + lane];
            unsigned vd = vals[o3 + lane];
            PROC(va) PROC(vb) PROC(vc) PROC(vd)
        }
        for (; r < deg; ++r) {
            unsigned v = vals[(long)eix[r] * 52 + lane];
            PROC(v)
        }
#undef PROC
    }
    if (lane < 48) {
        float r0 = (deg > 0) ? 1.f / d0 : 0.f;
        float r1 = (deg > 0) ? 1.f / d1 : 0.f;
        float r2 = (deg > 0) ? 1.f / d2 : 0.f;
        float r3 = (deg > 0) ? 1.f / d3 : 0.f;
        Tls[wv][0][2 * lane] = s0[0] * r0; Tls[wv][0][2 * lane + 1] = s1[0] * r0;
        Tls[wv][1][2 * lane] = s0[1] * r1; Tls[wv][1][2 * lane + 1] = s1[1] * r1;
        Tls[wv][2][2 * lane] = s0[2] * r2; Tls[wv][2][2 * lane + 1] = s1[2] * r2;
        Tls[wv][3][2 * lane] = s0[3] * r3; Tls[wv][3][2 * lane + 1] = s1[3] * r3;
    }
    // Same-wave LDS producer/consumer for Tls[wv]: lgkmcnt wait is
    // compiler-inserted; no block barrier needed. Wvs was barriered above.
    if (nvalid) {
        if (lane < 48) {
            int j = 2 * lane;                      // output cols j, j+1
            int h = lane / 12;                     // head (pairs never straddle)
            float a0 = bv[j], a1 = bv[j + 1];
            const float* Th = &Tls[wv][h][0];
#pragma unroll 4
            for (int k = 0; k < 96; ++k) {
                float t = Th[k];                   // wave-uniform: LDS broadcast
                float2 w = *(const float2*)&Wvs[k][j];  // 2-way alias: free
                a0 += t * w.x; a1 += t * w.y;
            }
            float2 o = (deg > 0) ? make_float2(a0, a1) : make_float2(0.f, 0.f);
            *(float2*)(agg + (long)node * 96 + j) = o;
        } else if (lane == 48) {
            cntF[node] = (float)deg;
        }
    }
}

// out = leaky_relu([x | agg | count] @ W_out + b_out)
// R11: coalesced float4 staging (transposed LDS writes); s_in padded to 68.
__global__ __launch_bounds__(256, 4)
void node_kernel(const float* __restrict__ x, const float* __restrict__ aggW,
                 const float* __restrict__ cntF,
                 const float* __restrict__ Wo, const float* __restrict__ bo,
                 float* __restrict__ out, int N)
{
    __shared__ float s_in[161][68];   // 272B rows: 16B-aligned float4 reads
    int n0 = blockIdx.x * 64;
    int j0 = blockIdx.y * 64;

    // x rows: 64 rows x 16 float4, lanes read consecutive float4s (coalesced)
    for (int idx = threadIdx.x; idx < 64 * 16; idx += 256) {
        int row = idx >> 4, f4 = idx & 15;
        int n = n0 + row;
        float4 v = make_float4(0.f, 0.f, 0.f, 0.f);
        if (n < N) v = ((const float4*)(x + (long)n * 64))[f4];
        s_in[4 * f4 + 0][row] = v.x; s_in[4 * f4 + 1][row] = v.y;
        s_in[4 * f4 + 2][row] = v.z; s_in[4 * f4 + 3][row] = v.w;
    }
    // agg rows: 64 rows x 24 float4, coalesced
    for (int idx = threadIdx.x; idx < 64 * 24; idx += 256) {
        int row = idx / 24, c4 = idx % 24;
        int n = n0 + row;
        float4 v = make_float4(0.f, 0.f, 0.f, 0.f);
        if (n < N) v = ((const float4*)(aggW + (long)n * 96))[c4];
        s_in[64 + 4 * c4 + 0][row] = v.x; s_in[64 + 4 * c4 + 1][row] = v.y;
        s_in[64 + 4 * c4 + 2][row] = v.z; s_in[64 + 4 * c4 + 3][row] = v.w;
    }
    if (threadIdx.x < 64) {
        int n = n0 + threadIdx.x;
        s_in[160][threadIdx.x] = (n < N) ? cntF[n] : 0.f;
    }
    __syncthreads();

    int tj = threadIdx.x & 15;
    int tn = threadIdx.x >> 4;
    float acc[4][4];
#pragma unroll
    for (int i = 0; i < 4; ++i)
#pragma unroll
        for (int c = 0; c < 4; ++c) acc[i][c] = 0.f;

    const float* Wcol = Wo + j0 + tj * 4;
    for (int k = 0; k < 161; ++k) {
        float4 w  = *(const float4*)(Wcol + (long)k * 128);
        float4 iv = *(const float4*)&s_in[k][tn * 4];
        acc[0][0] += iv.x * w.x; acc[0][1] += iv.x * w.y; acc[0][2] += iv.x * w.z; acc[0][3] += iv.x * w.w;
        acc[1][0] += iv.y * w.x; acc[1][1] += iv.y * w.y; acc[1][2] += iv.y * w.z; acc[1][3] += iv.y * w.w;
        acc[2][0] += iv.z * w.x; acc[2][1] += iv.z * w.y; acc[2][2] += iv.z * w.z; acc[2][3] += iv.z * w.w;
        acc[3][0] += iv.w * w.x; acc[3][1] += iv.w * w.y; acc[3][2] += iv.w * w.z; acc[3][3] += iv.w * w.w;
    }
    float4 b = *(const float4*)(bo + j0 + tj * 4);
#pragma unroll
    for (int i = 0; i < 4; ++i) {
        int n = n0 + tn * 4 + i;
        if (n < N) {
            float4 o;
            o.x = lrelu(acc[i][0] + b.x);
            o.y = lrelu(acc[i][1] + b.y);
            o.z = lrelu(acc[i][2] + b.z);
            o.w = lrelu(acc[i][3] + b.w);
            *(float4*)(out + (long)n * 128 + j0 + tj * 4) = o;
        }
    }
}

// ---------------- fallback (round-2 atomic path, used if ws too small) -----
__global__ __launch_bounds__(256, 1)
void edge_atm_kernel(const float* __restrict__ x, const float* __restrict__ ea,
                     const int* __restrict__ ei,
                     const float* __restrict__ Wp, const float* __restrict__ bp,
                     const float* __restrict__ Wa, const float* __restrict__ ba,
                     const float* __restrict__ Wv, const float* __restrict__ bv,
                     float* __restrict__ aggW, float* __restrict__ denomW,
                     float* __restrict__ cntW, int E)
{
    int e = blockIdx.x * 256 + threadIdx.x;
    if (e >= E) return;
    int src = ei[e];
    int dst = ei[E + e];
    float4 S[24];
#pragma unroll
    for (int j = 0; j < 24; ++j) S[j] = ((const float4*)bp)[j];
    const float* xrow = x + (long)src * 64;
    const float* erow = ea + (long)e * 32;
#pragma unroll 1
    for (int kc = 0; kc < 6; ++kc) {
        const float* sp = (kc < 4) ? (xrow + kc * 16) : (erow + (kc - 4) * 16);
        const float* Wb = Wp + kc * 16 * 96;
#pragma unroll 1
        for (int i = 0; i < 4; ++i) {
            float4 cc = ((const float4*)sp)[i];
#pragma unroll
            for (int j = 0; j < 24; ++j) {
                float4 w0 = ((const float4*)(Wb + (4 * i + 0) * 96))[j];
                float4 w1 = ((const float4*)(Wb + (4 * i + 1) * 96))[j];
                float4 w2 = ((const float4*)(Wb + (4 * i + 2) * 96))[j];
                float4 w3 = ((const float4*)(Wb + (4 * i + 3) * 96))[j];
                S[j].x += cc.x * w0.x + cc.y * w1.x + cc.z * w2.x + cc.w * w3.x;
                S[j].y += cc.x * w0.y + cc.y * w1.y + cc.z * w2.y + cc.w * w3.y;
                S[j].z += cc.x * w0.z + cc.y * w1.z + cc.z * w2.z + cc.w * w3.z;
                S[j].w += cc.x * w0.w + cc.y * w1.w + cc.z * w2.w + cc.w * w3.w;
            }
        }
    }
#pragma unroll
    for (int j = 0; j < 24; ++j) {
        S[j].x = lrelu(S[j].x); S[j].y = lrelu(S[j].y);
        S[j].z = lrelu(S[j].z); S[j].w = lrelu(S[j].w);
    }
    float l0 = ba[0], l1 = ba[1], l2 = ba[2], l3 = ba[3];
#pragma unroll
    for (int j = 0; j < 24; ++j) {
        float4 m = S[j];
        float4 w0 = ((const float4*)(Wa + (4 * j + 0) * 4))[0];
        float4 w1 = ((const float4*)(Wa + (4 * j + 1) * 4))[0];
        float4 w2 = ((const float4*)(Wa + (4 * j + 2) * 4))[0];
        float4 w3 = ((const float4*)(Wa + (4 * j + 3) * 4))[0];
        l0 += m.x * w0.x + m.y * w1.x + m.z * w2.x + m.w * w3.x;
        l1 += m.x * w0.y + m.y * w1.y + m.z * w2.y + m.w * w3.y;
        l2 += m.x * w0.z + m.y * w1.z + m.z * w2.z + m.w * w3.z;
        l3 += m.x * w0.w + m.y * w1.w + m.z * w2.w + m.w * w3.w;
    }
    float p0 = __expf(l0), p1 = __expf(l1), p2 = __expf(l2), p3 = __expf(l3);
    float* aggp = aggW + (long)dst * 96;
#pragma unroll 1
    for (int j4 = 0; j4 < 24; ++j4) {
        float4 acc = ((const float4*)bv)[j4];
        const float* Wc = Wv + 4 * j4;
#pragma unroll
        for (int j = 0; j < 24; ++j) {
            float4 m = S[j];
            float4 w0 = ((const float4*)(Wc + (4 * j + 0) * 96))[0];
            float4 w1 = ((const float4*)(Wc + (4 * j + 1) * 96))[0];
            float4 w2 = ((const float4*)(Wc + (4 * j + 2) * 96))[0];
            float4 w3 = ((const float4*)(Wc + (4 * j + 3) * 96))[0];
            acc.x += m.x * w0.x + m.y * w1.x + m.z * w2.x + m.w * w3.x;
            acc.y += m.x * w0.y + m.y * w1.y + m.z * w2.y + m.w * w3.y;
            acc.z += m.x * w0.z + m.y * w1.z + m.z * w2.z + m.w * w3.z;
            acc.w += m.x * w0.w + m.y * w1.w + m.z * w2.w + m.w * w3.w;
        }
        float ph = (j4 < 6) ? p0 : (j4 < 12) ? p1 : (j4 < 18) ? p2 : p3;
        unsafeAtomicAdd(aggp + 4 * j4 + 0, ph * acc.x);
        unsafeAtomicAdd(aggp + 4 * j4 + 1, ph * acc.y);
        unsafeAtomicAdd(aggp + 4 * j4 + 2, ph * acc.z);
        unsafeAtomicAdd(aggp + 4 * j4 + 3, ph * acc.w);
    }
    float* dn = denomW + (long)dst * 4;
    unsafeAtomicAdd(dn + 0, p0);
    unsafeAtomicAdd(dn + 1, p1);
    unsafeAtomicAdd(dn + 2, p2);
    unsafeAtomicAdd(dn + 3, p3);
    unsafeAtomicAdd(cntW + dst, 1.0f);
}

__global__ __launch_bounds__(256, 4)
void node_atm_kernel(const float* __restrict__ x, const float* __restrict__ aggW,
                     const float* __restrict__ denomW, const float* __restrict__ cntW,
                     const float* __restrict__ Wo, const float* __restrict__ bo,
                     float* __restrict__ out, int N)
{
    __shared__ float s_in[161][64];
    int n0 = blockIdx.x * 64;
    int j0 = blockIdx.y * 64;
    for (int p = threadIdx.x; p < 161 * 64; p += 256) {
        int k = p >> 6, nl = p & 63;
        int n = n0 + nl;
        float v = 0.f;
        if (n < N) {
            if (k < 64) v = x[(long)n * 64 + k];
            else if (k < 160) {
                int kk = k - 64;
                float d = denomW[n * 4 + (kk / 24)];
                v = d > 0.f ? aggW[(long)n * 96 + kk] / d : 0.f;
            } else v = cntW[n];
        }
        s_in[k][nl] = v;
    }
    __syncthreads();
    int tj = threadIdx.x & 15;
    int tn = threadIdx.x >> 4;
    float acc[4][4];
#pragma unroll
    for (int i = 0; i < 4; ++i)
#pragma unroll
        for (int c = 0; c < 4; ++c) acc[i][c] = 0.f;
    const float* Wcol = Wo + j0 + tj * 4;
    for (int k = 0; k < 161; ++k) {
        float4 w  = *(const float4*)(Wcol + (long)k * 128);
        float4 iv = *(const float4*)&s_in[k][tn * 4];
        acc[0][0] += iv.x * w.x; acc[0][1] += iv.x * w.y; acc[0][2] += iv.x * w.z; acc[0][3] += iv.x * w.w;
        acc[1][0] += iv.y * w.x; acc[1][1] += iv.y * w.y; acc[1][2] += iv.y * w.z; acc[1][3] += iv.y * w.w;
        acc[2][0] += iv.z * w.x; acc[2][1] += iv.z * w.y; acc[2][2] += iv.z * w.z; acc[2][3] += iv.z * w.w;
        acc[3][0] += iv.w * w.x; acc[3][1] += iv.w * w.y; acc[3][2] += iv.w * w.z; acc[3][3] += iv.w * w.w;
    }
    float4 b = *(const float4*)(bo + j0 + tj * 4);
#pragma unroll
    for (int i = 0; i < 4; ++i) {
        int n = n0 + tn * 4 + i;
        if (n < N) {
            float4 o;
            o.x = lrelu(acc[i][0] + b.x);
            o.y = lrelu(acc[i][1] + b.y);
            o.z = lrelu(acc[i][2] + b.z);
            o.w = lrelu(acc[i][3] + b.w);
            *(float4*)(out + (long)n * 128 + j0 + tj * 4) = o;
        }
    }
}

extern "C" void kernel_launch(void* const* d_in, const int* in_sizes, int n_in,
                              void* d_out, int out_size, void* d_ws, size_t ws_size,
                              hipStream_t stream)
{
    const float* x  = (const float*)d_in[0];
    const float* ea = (const float*)d_in[1];
    const int*   ei = (const int*)d_in[2];
    const float* Wp = (const float*)d_in[3];
    const float* bp = (const float*)d_in[4];
    const float* Wa = (const float*)d_in[5];
    const float* ba = (const float*)d_in[6];
    const float* Wv = (const float*)d_in[7];
    const float* bv = (const float*)d_in[8];
    const float* Wo = (const float*)d_in[9];
    const float* bo = (const float*)d_in[10];
    float* out = (float*)d_out;

    int N = in_sizes[0] / 64;
    int E = in_sizes[2] / 2;
    int NB = (N + 1023) / 1024;

    // vals | U/agg(alias) | cntF | cnti | offs | curs | bsum | eidx
    size_t need = (size_t)E * 52 * 4 + (size_t)N * 96 * 4 + (size_t)N * 4 * 4
                + (size_t)NB * 4 + (size_t)E * 4;

    if (ws_size >= need) {
        unsigned* vals = (unsigned*)d_ws;
        float* Uagg = (float*)(vals + (long)E * 52);   // U, later overwritten as agg
        float* cntF = Uagg + (long)N * 96;
        int*   cnti = (int*)(cntF + N);
        int*   offs = cnti + N;
        int*   curs = offs + N;
        int*   bsum = curs + N;
        int*   eidx = bsum + NB;

        hipMemsetAsync(cnti, 0, (size_t)N * sizeof(int), stream);
        hist_kernel<<<(E + 255) / 256, 256, 0, stream>>>(ei, cnti, E);
        if (NB <= 1024) {
            blocksum_kernel<<<NB, 256, 0, stream>>>(cnti, bsum, N);
            bscan_kernel<<<1, 1024, 0, stream>>>(bsum, NB);
            offs_kernel<<<NB, 1024, 0, stream>>>(cnti, bsum, offs, curs, N);
        } else {
            scan_kernel<<<1, 1024, 0, stream>>>(cnti, offs, curs, N);
        }
        pre_kernel<<<(N + 63) / 64, 256, 0, stream>>>(x, Wp, bp, Uagg, N);
        edge_msg_kernel<<<(2 * E + 255) / 256, 256, 0, stream>>>(
            Uagg, ea, ei, Wp, Wa, ba, vals, curs, eidx, E);
        gather_kernel<<<(N + 7) / 8, 512, 0, stream>>>(
            vals, offs, cnti, eidx, Wv, bv, Uagg, cntF, N);
        dim3 ng((N + 63) / 64, 2);
        node_kernel<<<ng, 256, 0, stream>>>(x, Uagg, cntF, Wo, bo, out, N);
    } else {
        float* aggW   = (float*)d_ws;
        float* denomW = aggW + (long)N * 96;
        float* cntW   = denomW + (long)N * 4;
        long zn = (long)N * 101;
        int  zb = (int)(((zn + 3) / 4 + 255) / 256);
        zero_kernel<<<zb, 256, 0, stream>>>(aggW, zn);
        edge_atm_kernel<<<(E + 255) / 256, 256, 0, stream>>>(
            x, ea, ei, Wp, bp, Wa, ba, Wv, bv, aggW, denomW, cntW, E);
        dim3 ng((N + 63) / 64, 2);
        node_atm_kernel<<<ng, 256, 0, stream>>>(x, aggW, denomW, cntW, Wo, bo, out, N);
    }
}